// Round 8
// baseline (469.543 us; speedup 1.0000x reference)
//
#include <hip/hip_runtime.h>
#include <math.h>

#define PI_F 3.14159265358979323846f

static constexpr int L_ = 512, D_ = 768, H_ = 12, DH_ = 64;
static constexpr int BL_ = 2048;            // B*L
static constexpr int BLD_ = BL_ * D_;       // 1572864
static constexpr int NC_ = 8;               // chunks (512/64)
static constexpr int BH_ = 48;              // B*H

__global__ void sentinel_kernel(float* out, float code, float aux) {
  out[0] = code; out[1] = aux;
}

// ---------------- LN stats only: per-row mu, rs (normalization fused into QKV) ----
__global__ __launch_bounds__(256) void ln_stats(const float* __restrict__ x,
                                                float* __restrict__ murs) {
  int row = blockIdx.x, tid = threadIdx.x;
  const float* xr = x + (size_t)row * D_;
  float v0 = xr[tid], v1 = xr[tid + 256], v2 = xr[tid + 512];
  float s = v0 + v1 + v2;
  float s2 = v0 * v0 + v1 * v1 + v2 * v2;
#pragma unroll
  for (int off = 32; off > 0; off >>= 1) { s += __shfl_xor(s, off); s2 += __shfl_xor(s2, off); }
  __shared__ float red[8];
  if ((tid & 63) == 0) { red[tid >> 6] = s; red[4 + (tid >> 6)] = s2; }
  __syncthreads();
  if (tid == 0) {
    float st = red[0] + red[1] + red[2] + red[3];
    float qt = red[4] + red[5] + red[6] + red[7];
    float mu = st * (1.0f / D_);
    float var = qt * (1.0f / D_) - mu * mu;
    murs[2 * row] = mu;
    murs[2 * row + 1] = rsqrtf(var + 1e-5f);
  }
}

// ---------------- fp32 GEMM 128x64 tile, 8x4/thread ----------------
// MODE 0: A = LayerNorm(x) applied on-the-fly (murs/lg/lb); epilogue +bias,
//         elu+1 on q,k sections; split O0/O1/O2 (stride 768). N=2304.
// MODE 2: plain A; +bias -> O0 (stride N).
template <int MODE>
__global__ __launch_bounds__(256) void gemm_big(const float* __restrict__ A,
                                                const float* __restrict__ murs,
                                                const float* __restrict__ lg,
                                                const float* __restrict__ lb,
                                                const float* __restrict__ Bm,
                                                const float* __restrict__ bias,
                                                float* __restrict__ O0,
                                                float* __restrict__ O1,
                                                float* __restrict__ O2,
                                                int N, int K) {
  __shared__ float As[16][132];   // [k][row], 132 stride: write 2-way, read broadcast
  __shared__ float Bs[16][68];
  int tid = threadIdx.x;
  int tx = tid & 15, ty = tid >> 4;
  int row0 = blockIdx.y * 128, col0 = blockIdx.x * 64;
  float acc[8][4] = {};
  int ar = tid >> 1, ak = (tid & 1) * 8;   // A: 128 rows x 16 k, 8 floats/thread
  int bk = tid >> 4, bc = (tid & 15) * 4;  // B: 16 k x 64 cols, 4 floats/thread
  float mu = 0.f, rs = 0.f;
  if (MODE == 0) {
    float2 m2 = *(const float2*)&murs[2 * (row0 + ar)];
    mu = m2.x; rs = m2.y;
  }
  const float* Arow = A + (size_t)(row0 + ar) * K;
  for (int k0 = 0; k0 < K; k0 += 16) {
    float4 a0 = *(const float4*)&Arow[k0 + ak];
    float4 a1 = *(const float4*)&Arow[k0 + ak + 4];
    if (MODE == 0) {
      float4 g0 = *(const float4*)&lg[k0 + ak];
      float4 g1 = *(const float4*)&lg[k0 + ak + 4];
      float4 c0 = *(const float4*)&lb[k0 + ak];
      float4 c1 = *(const float4*)&lb[k0 + ak + 4];
      a0.x = (a0.x - mu) * rs * g0.x + c0.x;
      a0.y = (a0.y - mu) * rs * g0.y + c0.y;
      a0.z = (a0.z - mu) * rs * g0.z + c0.z;
      a0.w = (a0.w - mu) * rs * g0.w + c0.w;
      a1.x = (a1.x - mu) * rs * g1.x + c1.x;
      a1.y = (a1.y - mu) * rs * g1.y + c1.y;
      a1.z = (a1.z - mu) * rs * g1.z + c1.z;
      a1.w = (a1.w - mu) * rs * g1.w + c1.w;
    }
    As[ak + 0][ar] = a0.x; As[ak + 1][ar] = a0.y;
    As[ak + 2][ar] = a0.z; As[ak + 3][ar] = a0.w;
    As[ak + 4][ar] = a1.x; As[ak + 5][ar] = a1.y;
    As[ak + 6][ar] = a1.z; As[ak + 7][ar] = a1.w;
    *(float4*)&Bs[bk][bc] = *(const float4*)&Bm[(size_t)(k0 + bk) * N + col0 + bc];
    __syncthreads();
#pragma unroll
    for (int kk = 0; kk < 16; ++kk) {
      float4 av0 = *(float4*)&As[kk][ty * 8];
      float4 av1 = *(float4*)&As[kk][ty * 8 + 4];
      float4 bv = *(float4*)&Bs[kk][tx * 4];
      acc[0][0] += av0.x * bv.x; acc[0][1] += av0.x * bv.y; acc[0][2] += av0.x * bv.z; acc[0][3] += av0.x * bv.w;
      acc[1][0] += av0.y * bv.x; acc[1][1] += av0.y * bv.y; acc[1][2] += av0.y * bv.z; acc[1][3] += av0.y * bv.w;
      acc[2][0] += av0.z * bv.x; acc[2][1] += av0.z * bv.y; acc[2][2] += av0.z * bv.z; acc[2][3] += av0.z * bv.w;
      acc[3][0] += av0.w * bv.x; acc[3][1] += av0.w * bv.y; acc[3][2] += av0.w * bv.z; acc[3][3] += av0.w * bv.w;
      acc[4][0] += av1.x * bv.x; acc[4][1] += av1.x * bv.y; acc[4][2] += av1.x * bv.z; acc[4][3] += av1.x * bv.w;
      acc[5][0] += av1.y * bv.x; acc[5][1] += av1.y * bv.y; acc[5][2] += av1.y * bv.z; acc[5][3] += av1.y * bv.w;
      acc[6][0] += av1.z * bv.x; acc[6][1] += av1.z * bv.y; acc[6][2] += av1.z * bv.z; acc[6][3] += av1.z * bv.w;
      acc[7][0] += av1.w * bv.x; acc[7][1] += av1.w * bv.y; acc[7][2] += av1.w * bv.z; acc[7][3] += av1.w * bv.w;
    }
    __syncthreads();
  }
  float4 bi = *(const float4*)&bias[col0 + tx * 4];
  if (MODE == 0) {
    int sec = col0 / 768;   // uniform per block (64 | 768)
    float* O = (sec == 0) ? O0 : ((sec == 1) ? O1 : O2);
    int lc = col0 - sec * 768 + tx * 4;
#pragma unroll
    for (int i = 0; i < 8; ++i) {
      int r = row0 + ty * 8 + i;
      float4 v;
      v.x = acc[i][0] + bi.x; v.y = acc[i][1] + bi.y;
      v.z = acc[i][2] + bi.z; v.w = acc[i][3] + bi.w;
      if (sec < 2) {  // elu(x)+1
        v.x = (v.x > 0.f) ? v.x + 1.f : expf(v.x);
        v.y = (v.y > 0.f) ? v.y + 1.f : expf(v.y);
        v.z = (v.z > 0.f) ? v.z + 1.f : expf(v.z);
        v.w = (v.w > 0.f) ? v.w + 1.f : expf(v.w);
      }
      *(float4*)&O[(size_t)r * 768 + lc] = v;
    }
  } else {
#pragma unroll
    for (int i = 0; i < 8; ++i) {
      int r = row0 + ty * 8 + i;
      float4 v;
      v.x = acc[i][0] + bi.x; v.y = acc[i][1] + bi.y;
      v.z = acc[i][2] + bi.z; v.w = acc[i][3] + bi.w;
      *(float4*)&O0[(size_t)r * N + col0 + tx * 4] = v;
    }
  }
}

// ---------------- fp32 tiled GEMM 64x64 (bottleneck MLP), MODE 1: silu ----------------
__global__ __launch_bounds__(256) void gemm_silu(const float* __restrict__ A,
                                                 const float* __restrict__ Bm,
                                                 float* __restrict__ O0,
                                                 int N, int K) {
  __shared__ float As[16][68];
  __shared__ float Bs[16][68];
  int tid = threadIdx.x;
  int tx = tid & 15, ty = tid >> 4;
  int row0 = blockIdx.y * 64, col0 = blockIdx.x * 64;
  float acc[4][4] = {};
  int ar = tid >> 2, ak = (tid & 3) * 4;
  int bk = tid >> 4, bc = (tid & 15) * 4;
  for (int k0 = 0; k0 < K; k0 += 16) {
    float4 a4 = *(const float4*)&A[(size_t)(row0 + ar) * K + k0 + ak];
    As[ak + 0][ar] = a4.x; As[ak + 1][ar] = a4.y;
    As[ak + 2][ar] = a4.z; As[ak + 3][ar] = a4.w;
    *(float4*)&Bs[bk][bc] = *(const float4*)&Bm[(size_t)(k0 + bk) * N + col0 + bc];
    __syncthreads();
#pragma unroll
    for (int kk = 0; kk < 16; ++kk) {
      float4 av = *(float4*)&As[kk][ty * 4];
      float4 bv = *(float4*)&Bs[kk][tx * 4];
      acc[0][0] += av.x * bv.x; acc[0][1] += av.x * bv.y; acc[0][2] += av.x * bv.z; acc[0][3] += av.x * bv.w;
      acc[1][0] += av.y * bv.x; acc[1][1] += av.y * bv.y; acc[1][2] += av.y * bv.z; acc[1][3] += av.y * bv.w;
      acc[2][0] += av.z * bv.x; acc[2][1] += av.z * bv.y; acc[2][2] += av.z * bv.z; acc[2][3] += av.z * bv.w;
      acc[3][0] += av.w * bv.x; acc[3][1] += av.w * bv.y; acc[3][2] += av.w * bv.z; acc[3][3] += av.w * bv.w;
    }
    __syncthreads();
  }
#pragma unroll
  for (int ii = 0; ii < 4; ++ii) {
    int r = row0 + ty * 4 + ii;
    float4 v;
    v.x = acc[ii][0]; v.y = acc[ii][1]; v.z = acc[ii][2]; v.w = acc[ii][3];
    v.x = v.x / (1.f + expf(-v.x));
    v.y = v.y / (1.f + expf(-v.y));
    v.z = v.z / (1.f + expf(-v.z));
    v.w = v.w / (1.f + expf(-v.w));
    *(float4*)&O0[(size_t)r * N + col0 + tx * 4] = v;
  }
}

// ---------------- params: h1 @ W_b2 -> gate / decay coefficients ----------------
__global__ __launch_bounds__(64) void params_kernel(const float* __restrict__ h1,
                                                    const float* __restrict__ Wb2,
                                                    const float* __restrict__ temp_p,
                                                    float* __restrict__ gate_out,
                                                    float* __restrict__ cg,
                                                    float* __restrict__ ce,
                                                    float* __restrict__ ld) {
  int t = blockIdx.x;
  int tid = threadIdx.x;
  __shared__ float hs[128];
  __shared__ float ps[60];
  *(float2*)&hs[tid * 2] = *(const float2*)&h1[(size_t)t * 128 + tid * 2];
  __syncthreads();
  if (tid < 60) {
    float acc = 0.f;
#pragma unroll 4
    for (int k = 0; k < 128; ++k) acc += hs[k] * Wb2[k * 60 + tid];
    ps[tid] = acc;
  }
  __syncthreads();
  if (tid < 12) {
    float p0 = ps[tid * 5 + 0], p1 = ps[tid * 5 + 1], p2 = ps[tid * 5 + 2];
    float p3 = ps[tid * 5 + 3], p4 = ps[tid * 5 + 4];
    float sa = 1.f / (1.f + expf(-p0));
    float sp = tanhf(p1) * PI_F;
    float ca = 1.f / (1.f + expf(-p2));
    float cp = tanhf(p3) * PI_F;
    float dec = 0.5f + 0.49f / (1.f + expf(-p4));
    float tmp = fminf(fmaxf(temp_p[0], 0.1f), 2.0f);
    float inter = tanhf(sa * ca * cosf(sp - cp)) * tmp;
    float gate = 1.f / (1.f + expf(-inter));
    gate_out[t * 12 + tid] = gate;
    int b = t >> 9, l = t & 511;
    int bhl = (b * 12 + tid) * L_ + l;
    float ema = 1.f - dec;
    cg[bhl] = ema * (1.f + gate);
    ce[bhl] = ema;
    ld[bhl] = logf(dec + 1e-8f);
  }
}

// ---------------- cumulative log-decay + chunk-end values ----------------
__global__ __launch_bounds__(64) void cld_kernel(const float* __restrict__ ld,
                                                 float* __restrict__ cld,
                                                 float* __restrict__ cEnd) {
  int bh = blockIdx.x;
  int lane = threadIdx.x;
  const float* src = ld + (size_t)bh * L_;
  float v[8];
  float s = 0.f;
#pragma unroll
  for (int i = 0; i < 8; ++i) { v[i] = src[lane * 8 + i]; s += v[i]; }
  float tot = s;
#pragma unroll
  for (int off = 1; off < 64; off <<= 1) {
    float n = __shfl_up(tot, off);
    if (lane >= off) tot += n;
  }
  float run = tot - s;
  float out7 = 0.f;
#pragma unroll
  for (int i = 0; i < 8; ++i) {
    run += v[i];
    float o = fmaxf(run, -85.f);
    cld[(size_t)bh * L_ + lane * 8 + i] = o;
    out7 = o;
  }
  if ((lane & 7) == 7) cEnd[bh * NC_ + (lane >> 3)] = out7;
}

// ---------------- overflow scan: exact fp32 mirror of ref's z cumsum ----------------
__global__ __launch_bounds__(64) void infscan_kernel(const float* __restrict__ kf,
                                                     const float* __restrict__ ce,
                                                     const float* __restrict__ cld,
                                                     int* __restrict__ tstar) {
  int bh = blockIdx.x;
  int b = bh / H_, h = bh - b * H_;
  int e = threadIdx.x;
  float cz = 0.f;
  int tf = L_;
  for (int t = 0; t < L_; ++t) {
    int idx = bh * L_ + t;
    float s = ce[idx] * expf(-cld[idx]);
    float kv = kf[(size_t)(b * L_ + t) * D_ + h * DH_ + e];
    cz = cz + kv * s;
    if (tf == L_ && isinf(cz)) tf = t;
  }
#pragma unroll
  for (int off = 1; off < 64; off <<= 1) tf = min(tf, __shfl_xor(tf, off));
  if (e == 0) tstar[bh] = tf;
}

// ---------------- per-chunk summaries T_c (64x64) and z_c (64) ----------------
__global__ __launch_bounds__(256) void chunk_sum_kernel(const float* __restrict__ kf,
                                                        const float* __restrict__ vf,
                                                        const float* __restrict__ cg,
                                                        const float* __restrict__ ce,
                                                        const float* __restrict__ cld,
                                                        const float* __restrict__ cEnd,
                                                        float* __restrict__ T,
                                                        float* __restrict__ zc) {
  int blk = blockIdx.x;
  int c = blk & 7, bh = blk >> 3;
  int b = bh / H_, h = bh - b * H_;
  int tid = threadIdx.x;
  __shared__ float kfs[64][68];
  __shared__ float vfs[64][68];
  __shared__ float wv[64], wz[64];
  float cend = cEnd[blk];
  if (tid < 64) {
    int idx = bh * L_ + c * 64 + tid;
    float w = expf(cend - cld[idx]);
    wv[tid] = cg[idx] * w;
    wz[tid] = ce[idx] * w;
  }
  __syncthreads();
  int t = tid >> 2, g4 = (tid & 3) * 16;
  size_t rowb = (size_t)(b * L_ + c * 64 + t) * D_ + h * 64 + g4;
  float wvt = wv[t];
#pragma unroll
  for (int i = 0; i < 4; ++i) {
    *(float4*)&kfs[t][g4 + 4 * i] = *(const float4*)&kf[rowb + 4 * i];
    float4 vv = *(const float4*)&vf[rowb + 4 * i];
    vv.x *= wvt; vv.y *= wvt; vv.z *= wvt; vv.w *= wvt;
    *(float4*)&vfs[t][g4 + 4 * i] = vv;
  }
  __syncthreads();
  int d = tid >> 2, eb = (tid & 3) * 16;
  float4 a0 = {}, a1 = {}, a2 = {}, a3 = {};
  for (int tt = 0; tt < 64; ++tt) {
    float kd = kfs[tt][d];
    float4 x0 = *(float4*)&vfs[tt][eb + 0];
    float4 x1 = *(float4*)&vfs[tt][eb + 4];
    float4 x2 = *(float4*)&vfs[tt][eb + 8];
    float4 x3 = *(float4*)&vfs[tt][eb + 12];
    a0.x += kd * x0.x; a0.y += kd * x0.y; a0.z += kd * x0.z; a0.w += kd * x0.w;
    a1.x += kd * x1.x; a1.y += kd * x1.y; a1.z += kd * x1.z; a1.w += kd * x1.w;
    a2.x += kd * x2.x; a2.y += kd * x2.y; a2.z += kd * x2.z; a2.w += kd * x2.w;
    a3.x += kd * x3.x; a3.y += kd * x3.y; a3.z += kd * x3.z; a3.w += kd * x3.w;
  }
  size_t tb = (size_t)blk * 4096 + (size_t)d * 64 + eb;
  *(float4*)&T[tb + 0] = a0;
  *(float4*)&T[tb + 4] = a1;
  *(float4*)&T[tb + 8] = a2;
  *(float4*)&T[tb + 12] = a3;
  if (tid < 64) {
    float za = 0.f;
#pragma unroll 8
    for (int tt = 0; tt < 64; ++tt) za += kfs[tt][tid] * wz[tt];
    zc[blk * 64 + tid] = za;
  }
}

// ---------------- inter-chunk scan (IN-PLACE: Sprev aliases T) ----------------
__global__ __launch_bounds__(256) void scan_kernel(float* __restrict__ T,
                                                   const float* __restrict__ zc,
                                                   const float* __restrict__ cEnd,
                                                   float* __restrict__ zprev) {
  int bh = blockIdx.x, tid = threadIdx.x;
  float4 s0 = {}, s1 = {}, s2 = {}, s3 = {};
  float zs = 0.f;
  float prevEnd = 0.f;
  for (int c = 0; c < NC_; ++c) {
    int blk = bh * NC_ + c;
    float r = expf(cEnd[blk] - prevEnd);
    prevEnd = cEnd[blk];
    size_t base = (size_t)blk * 4096 + (size_t)tid * 16;
    float4 t0 = *(const float4*)&T[base + 0];
    float4 t1 = *(const float4*)&T[base + 4];
    float4 t2 = *(const float4*)&T[base + 8];
    float4 t3 = *(const float4*)&T[base + 12];
    *(float4*)&T[base + 0] = s0;
    *(float4*)&T[base + 4] = s1;
    *(float4*)&T[base + 8] = s2;
    *(float4*)&T[base + 12] = s3;
    s0.x = s0.x * r + t0.x; s0.y = s0.y * r + t0.y; s0.z = s0.z * r + t0.z; s0.w = s0.w * r + t0.w;
    s1.x = s1.x * r + t1.x; s1.y = s1.y * r + t1.y; s1.z = s1.z * r + t1.z; s1.w = s1.w * r + t1.w;
    s2.x = s2.x * r + t2.x; s2.y = s2.y * r + t2.y; s2.z = s2.z * r + t2.z; s2.w = s2.w * r + t2.w;
    s3.x = s3.x * r + t3.x; s3.y = s3.y * r + t3.y; s3.z = s3.z * r + t3.z; s3.w = s3.w * r + t3.w;
    if (tid < 64) {
      zprev[blk * 64 + tid] = zs;
      zs = zs * r + zc[blk * 64 + tid];
    }
  }
}

// ---------------- per-chunk outputs (+ overflow mask), /den, LayerNorm(DH) ----------------
__global__ __launch_bounds__(256) void chunk_out_kernel(const float* __restrict__ qf,
                                                        const float* __restrict__ kf,
                                                        const float* __restrict__ vf,
                                                        const float* __restrict__ cg,
                                                        const float* __restrict__ ce,
                                                        const float* __restrict__ cld,
                                                        const float* __restrict__ cEnd,
                                                        const float* __restrict__ Sprev,
                                                        const float* __restrict__ zprev,
                                                        const int* __restrict__ tstar,
                                                        const float* __restrict__ mg,
                                                        const float* __restrict__ mb,
                                                        float* __restrict__ attn) {
  int blk = blockIdx.x;
  int c = blk & 7, bh = blk >> 3;
  int b = bh / H_, h = bh - b * H_;
  int tid = threadIdx.x;
  __shared__ float qfs[64][68];
  __shared__ float kfs[64][68];  // reused to hold M after score phase
  __shared__ float vfs[64][68];
  __shared__ float cldS[64], cgS[64], ceS[64], zS[64];
  int t = tid >> 2, g4 = (tid & 3) * 16;
  size_t rowb = (size_t)(b * L_ + c * 64 + t) * D_ + h * 64 + g4;
#pragma unroll
  for (int i = 0; i < 4; ++i) {
    *(float4*)&qfs[t][g4 + 4 * i] = *(const float4*)&qf[rowb + 4 * i];
    *(float4*)&kfs[t][g4 + 4 * i] = *(const float4*)&kf[rowb + 4 * i];
    *(float4*)&vfs[t][g4 + 4 * i] = *(const float4*)&vf[rowb + 4 * i];
  }
  if (tid < 64) {
    int idx = bh * L_ + c * 64 + tid;
    cldS[tid] = cld[idx];
    cgS[tid] = cg[idx];
    ceS[tid] = ce[idx];
    zS[tid] = zprev[blk * 64 + tid];
  }
  __syncthreads();
  float prevEnd = (c == 0) ? 0.f : cEnd[blk - 1];
  int ts = tstar[bh];
  int i = tid >> 2, jb = (tid & 3) * 16;
  float sc[16];
#pragma unroll
  for (int jj = 0; jj < 16; ++jj) sc[jj] = 0.f;
  for (int d = 0; d < 64; d += 4) {
    float4 q4 = *(float4*)&qfs[i][d];
#pragma unroll
    for (int jj = 0; jj < 16; ++jj) {
      float4 k4 = *(float4*)&kfs[jb + jj][d];
      sc[jj] += q4.x * k4.x + q4.y * k4.y + q4.z * k4.z + q4.w * k4.w;
    }
  }
  float cldi = cldS[i];
  float den = 0.f;
  float mvals[16];
#pragma unroll
  for (int jj = 0; jj < 16; ++jj) {
    int j = jb + jj;
    float w = (j <= i) ? expf(cldi - cldS[j]) : 0.f;
    float sw = sc[jj] * w;
    den += sw * ceS[j];
    mvals[jj] = sw * cgS[j];
  }
  float dz = 0.f;
#pragma unroll
  for (int dd = 0; dd < 16; ++dd) dz += qfs[i][jb + dd] * zS[jb + dd];
  den += __shfl_xor(den, 1); den += __shfl_xor(den, 2);
  dz += __shfl_xor(dz, 1);  dz += __shfl_xor(dz, 2);
  float wi = expf(cldi - prevEnd);
  den += wi * dz + 1e-6f;
  __syncthreads();
#pragma unroll
  for (int jj = 0; jj < 16; ++jj) kfs[i][jb + jj] = mvals[jj];
  __syncthreads();
  float4 o0 = {}, o1 = {}, o2 = {}, o3 = {};
  for (int j = 0; j < 64; ++j) {
    float m = kfs[i][j];
    float4 x0 = *(float4*)&vfs[j][jb + 0];
    float4 x1 = *(float4*)&vfs[j][jb + 4];
    float4 x2 = *(float4*)&vfs[j][jb + 8];
    float4 x3 = *(float4*)&vfs[j][jb + 12];
    o0.x += m * x0.x; o0.y += m * x0.y; o0.z += m * x0.z; o0.w += m * x0.w;
    o1.x += m * x1.x; o1.y += m * x1.y; o1.z += m * x1.z; o1.w += m * x1.w;
    o2.x += m * x2.x; o2.y += m * x2.y; o2.z += m * x2.z; o2.w += m * x2.w;
    o3.x += m * x3.x; o3.y += m * x3.y; o3.z += m * x3.z; o3.w += m * x3.w;
  }
  float4 p0 = {}, p1 = {}, p2 = {}, p3 = {};
  size_t sb = (size_t)blk * 4096;
  for (int d = 0; d < 64; ++d) {
    float qd = qfs[i][d];
    float4 x0 = *(const float4*)&Sprev[sb + d * 64 + jb + 0];
    float4 x1 = *(const float4*)&Sprev[sb + d * 64 + jb + 4];
    float4 x2 = *(const float4*)&Sprev[sb + d * 64 + jb + 8];
    float4 x3 = *(const float4*)&Sprev[sb + d * 64 + jb + 12];
    p0.x += qd * x0.x; p0.y += qd * x0.y; p0.z += qd * x0.z; p0.w += qd * x0.w;
    p1.x += qd * x1.x; p1.y += qd * x1.y; p1.z += qd * x1.z; p1.w += qd * x1.w;
    p2.x += qd * x2.x; p2.y += qd * x2.y; p2.z += qd * x2.z; p2.w += qd * x2.w;
    p3.x += qd * x3.x; p3.y += qd * x3.y; p3.z += qd * x3.z; p3.w += qd * x3.w;
  }
  size_t ob = (size_t)(b * L_ + c * 64 + i) * D_ + h * 64 + jb;
  if (c * 64 + i >= ts) {
#pragma unroll
    for (int q4i = 0; q4i < 4; ++q4i) {
      float4 w4;
      w4.x = mb[jb + q4i * 4 + 0]; w4.y = mb[jb + q4i * 4 + 1];
      w4.z = mb[jb + q4i * 4 + 2]; w4.w = mb[jb + q4i * 4 + 3];
      *(float4*)&attn[ob + q4i * 4] = w4;
    }
    return;
  }
  float inv = 1.0f / den;
  float o[16];
  o[0] = (o0.x + wi * p0.x) * inv;  o[1] = (o0.y + wi * p0.y) * inv;
  o[2] = (o0.z + wi * p0.z) * inv;  o[3] = (o0.w + wi * p0.w) * inv;
  o[4] = (o1.x + wi * p1.x) * inv;  o[5] = (o1.y + wi * p1.y) * inv;
  o[6] = (o1.z + wi * p1.z) * inv;  o[7] = (o1.w + wi * p1.w) * inv;
  o[8] = (o2.x + wi * p2.x) * inv;  o[9] = (o2.y + wi * p2.y) * inv;
  o[10] = (o2.z + wi * p2.z) * inv; o[11] = (o2.w + wi * p2.w) * inv;
  o[12] = (o3.x + wi * p3.x) * inv; o[13] = (o3.y + wi * p3.y) * inv;
  o[14] = (o3.z + wi * p3.z) * inv; o[15] = (o3.w + wi * p3.w) * inv;
  float s = 0.f, s2 = 0.f;
#pragma unroll
  for (int e2 = 0; e2 < 16; ++e2) { s += o[e2]; s2 += o[e2] * o[e2]; }
  s += __shfl_xor(s, 1);  s += __shfl_xor(s, 2);
  s2 += __shfl_xor(s2, 1); s2 += __shfl_xor(s2, 2);
  float mu = s * (1.f / 64.f);
  float var = s2 * (1.f / 64.f) - mu * mu;
  float rs = rsqrtf(var + 1e-5f);
#pragma unroll
  for (int q4i = 0; q4i < 4; ++q4i) {
    float4 w4;
    w4.x = (o[q4i * 4 + 0] - mu) * rs * mg[jb + q4i * 4 + 0] + mb[jb + q4i * 4 + 0];
    w4.y = (o[q4i * 4 + 1] - mu) * rs * mg[jb + q4i * 4 + 1] + mb[jb + q4i * 4 + 1];
    w4.z = (o[q4i * 4 + 2] - mu) * rs * mg[jb + q4i * 4 + 2] + mb[jb + q4i * 4 + 2];
    w4.w = (o[q4i * 4 + 3] - mu) * rs * mg[jb + q4i * 4 + 3] + mb[jb + q4i * 4 + 3];
    *(float4*)&attn[ob + q4i * 4] = w4;
  }
}

extern "C" void kernel_launch(void* const* d_in, const int* in_sizes, int n_in,
                              void* d_out, int out_size, void* d_ws, size_t ws_size,
                              hipStream_t stream) {
  const float* x     = (const float*)d_in[0];
  const float* Wqkv  = (const float*)d_in[1];
  const float* bqkv  = (const float*)d_in[2];
  const float* Wb1   = (const float*)d_in[3];
  const float* Wb2   = (const float*)d_in[4];
  const float* temp  = (const float*)d_in[5];
  const float* Wproj = (const float*)d_in[6];
  const float* bproj = (const float*)d_in[7];
  const float* lng   = (const float*)d_in[8];
  const float* lnb   = (const float*)d_in[9];
  const float* memg  = (const float*)d_in[10];
  const float* memb  = (const float*)d_in[11];
  float* out0 = (float*)d_out;
  float* gate = out0 + BLD_;

  static const int expect[12] = {1572864, 1769472, 2304, 98304, 7680, 1,
                                 589824, 768, 768, 768, 64, 64};
  int bad = (n_in == 12) ? -1 : 99;
  if (bad < 0) for (int i = 0; i < 12; ++i) if (in_sizes[i] != expect[i]) { bad = i; break; }
  size_t need = (size_t)(4 * BLD_ + 262144 + 4 * 24576) * sizeof(float);  // 26.61 MB (proven)
  if (bad >= 0) { sentinel_kernel<<<1, 1, 0, stream>>>(out0, 3.0e6f, (float)bad); return; }
  if (ws_size < need) { sentinel_kernel<<<1, 1, 0, stream>>>(out0, 1.0e6f, (float)(ws_size >> 20)); return; }

  float* ws   = (float*)d_ws;
  float* xn   = ws;                  // BLD_; holds murs (4096) until QKV, then T/Sprev
  float* qfb  = xn + BLD_;           // BLD_; reused as attn by chunk_out (same rows)
  float* kfb  = qfb + BLD_;
  float* vfb  = kfb + BLD_;
  float* h1   = vfb + BLD_;          // 262144; dead after params -> zc/zprev/cEnd/tstar
  float* cgb  = h1 + 262144;
  float* ceb  = cgb + 24576;
  float* ldb  = ceb + 24576;
  float* cldb = ldb + 24576;
  float* murs = xn;                  // 4096 floats; dead after QKV (T written later)
  float* Tb   = xn;                  // alias: T and (after in-place scan) Sprev
  float* zcb  = h1;
  float* zpv  = h1 + 24576;
  float* cEnd = h1 + 49152;          // 384
  int*   tstar = (int*)(h1 + 49536); // 48
  float* attn = qfb;                 // alias: chunk_out writes exactly the rows it read

  ln_stats<<<BL_, 256, 0, stream>>>(x, murs);
  gemm_silu<<<dim3(2, 32), 256, 0, stream>>>(x, Wb1, h1, 128, 768);
  params_kernel<<<BL_, 64, 0, stream>>>(h1, Wb2, temp, gate, cgb, ceb, ldb);
  cld_kernel<<<BH_, 64, 0, stream>>>(ldb, cldb, cEnd);
  gemm_big<0><<<dim3(36, 16), 256, 0, stream>>>(x, murs, lng, lnb, Wqkv, bqkv,
                                                qfb, kfb, vfb, 2304, 768);
  infscan_kernel<<<BH_, 64, 0, stream>>>(kfb, ceb, cldb, tstar);
  chunk_sum_kernel<<<BH_ * NC_, 256, 0, stream>>>(kfb, vfb, cgb, ceb, cldb, cEnd, Tb, zcb);
  scan_kernel<<<BH_, 256, 0, stream>>>(Tb, zcb, cEnd, zpv);
  chunk_out_kernel<<<BH_ * NC_, 256, 0, stream>>>(qfb, kfb, vfb, cgb, ceb, cldb, cEnd,
                                                  Tb, zpv, tstar, memg, memb, attn);
  gemm_big<2><<<dim3(12, 16), 256, 0, stream>>>(attn, nullptr, nullptr, nullptr, Wproj,
                                                bproj, out0, nullptr, nullptr, 768, 768);
}

// Round 9
// 466.880 us; speedup vs baseline: 1.0057x; 1.0057x over previous
//
#include <hip/hip_runtime.h>
#include <math.h>

#define PI_F 3.14159265358979323846f

static constexpr int L_ = 512, D_ = 768, H_ = 12, DH_ = 64;
static constexpr int BL_ = 2048;            // B*L
static constexpr int BLD_ = BL_ * D_;       // 1572864
static constexpr int NC_ = 8;               // chunks (512/64)
static constexpr int BH_ = 48;              // B*H

__global__ void sentinel_kernel(float* out, float code, float aux) {
  out[0] = code; out[1] = aux;
}

// ---------------- LN stats only: per-row mu, rs (normalization fused into QKV) ----
__global__ __launch_bounds__(256) void ln_stats(const float* __restrict__ x,
                                                float* __restrict__ murs) {
  int row = blockIdx.x, tid = threadIdx.x;
  const float* xr = x + (size_t)row * D_;
  float v0 = xr[tid], v1 = xr[tid + 256], v2 = xr[tid + 512];
  float s = v0 + v1 + v2;
  float s2 = v0 * v0 + v1 * v1 + v2 * v2;
#pragma unroll
  for (int off = 32; off > 0; off >>= 1) { s += __shfl_xor(s, off); s2 += __shfl_xor(s2, off); }
  __shared__ float red[8];
  if ((tid & 63) == 0) { red[tid >> 6] = s; red[4 + (tid >> 6)] = s2; }
  __syncthreads();
  if (tid == 0) {
    float st = red[0] + red[1] + red[2] + red[3];
    float qt = red[4] + red[5] + red[6] + red[7];
    float mu = st * (1.0f / D_);
    float var = qt * (1.0f / D_) - mu * mu;
    murs[2 * row] = mu;
    murs[2 * row + 1] = rsqrtf(var + 1e-5f);
  }
}

// ---------------- QKV GEMM: 64x64 tile, 128 threads, 8x4/thread, fused LN ----------
// A = LayerNorm(x) on the fly; epilogue +bias, elu+1 on q,k sections; split Oq/Ok/Ov.
__global__ __launch_bounds__(128) void gemm_qkv(const float* __restrict__ x,
                                                const float* __restrict__ murs,
                                                const float* __restrict__ lg,
                                                const float* __restrict__ lb,
                                                const float* __restrict__ Bm,
                                                const float* __restrict__ bias,
                                                float* __restrict__ Oq,
                                                float* __restrict__ Ok,
                                                float* __restrict__ Ov) {
  const int N = 2304, K = 768;
  __shared__ float As[16][68];   // [k][row]
  __shared__ float Bs[16][68];   // [k][col]
  int tid = threadIdx.x;
  int tx = tid & 15, ty = tid >> 4;          // tx 0..15 (cols), ty 0..7 (row groups)
  int row0 = blockIdx.y * 64, col0 = blockIdx.x * 64;
  float acc[8][4] = {};
  int ar = tid >> 1, ak = (tid & 1) * 8;     // A: row ar (0..63), k ak..ak+7
  int bk = tid >> 3, bc = (tid & 7) * 8;     // B: k-row bk (0..15), cols bc..bc+7
  float2 m2 = *(const float2*)&murs[2 * (row0 + ar)];
  float mu = m2.x, rs = m2.y;
  const float* Arow = x + (size_t)(row0 + ar) * K;
  for (int k0 = 0; k0 < K; k0 += 16) {
    float4 a0 = *(const float4*)&Arow[k0 + ak];
    float4 a1 = *(const float4*)&Arow[k0 + ak + 4];
    float4 g0 = *(const float4*)&lg[k0 + ak];
    float4 g1 = *(const float4*)&lg[k0 + ak + 4];
    float4 c0 = *(const float4*)&lb[k0 + ak];
    float4 c1 = *(const float4*)&lb[k0 + ak + 4];
    a0.x = (a0.x - mu) * rs * g0.x + c0.x;
    a0.y = (a0.y - mu) * rs * g0.y + c0.y;
    a0.z = (a0.z - mu) * rs * g0.z + c0.z;
    a0.w = (a0.w - mu) * rs * g0.w + c0.w;
    a1.x = (a1.x - mu) * rs * g1.x + c1.x;
    a1.y = (a1.y - mu) * rs * g1.y + c1.y;
    a1.z = (a1.z - mu) * rs * g1.z + c1.z;
    a1.w = (a1.w - mu) * rs * g1.w + c1.w;
    As[ak + 0][ar] = a0.x; As[ak + 1][ar] = a0.y;
    As[ak + 2][ar] = a0.z; As[ak + 3][ar] = a0.w;
    As[ak + 4][ar] = a1.x; As[ak + 5][ar] = a1.y;
    As[ak + 6][ar] = a1.z; As[ak + 7][ar] = a1.w;
    *(float4*)&Bs[bk][bc]     = *(const float4*)&Bm[(size_t)(k0 + bk) * N + col0 + bc];
    *(float4*)&Bs[bk][bc + 4] = *(const float4*)&Bm[(size_t)(k0 + bk) * N + col0 + bc + 4];
    __syncthreads();
#pragma unroll
    for (int kk = 0; kk < 16; ++kk) {
      float4 av0 = *(float4*)&As[kk][ty * 8];
      float4 av1 = *(float4*)&As[kk][ty * 8 + 4];
      float4 bv = *(float4*)&Bs[kk][tx * 4];
      acc[0][0] += av0.x * bv.x; acc[0][1] += av0.x * bv.y; acc[0][2] += av0.x * bv.z; acc[0][3] += av0.x * bv.w;
      acc[1][0] += av0.y * bv.x; acc[1][1] += av0.y * bv.y; acc[1][2] += av0.y * bv.z; acc[1][3] += av0.y * bv.w;
      acc[2][0] += av0.z * bv.x; acc[2][1] += av0.z * bv.y; acc[2][2] += av0.z * bv.z; acc[2][3] += av0.z * bv.w;
      acc[3][0] += av0.w * bv.x; acc[3][1] += av0.w * bv.y; acc[3][2] += av0.w * bv.z; acc[3][3] += av0.w * bv.w;
      acc[4][0] += av1.x * bv.x; acc[4][1] += av1.x * bv.y; acc[4][2] += av1.x * bv.z; acc[4][3] += av1.x * bv.w;
      acc[5][0] += av1.y * bv.x; acc[5][1] += av1.y * bv.y; acc[5][2] += av1.y * bv.z; acc[5][3] += av1.y * bv.w;
      acc[6][0] += av1.z * bv.x; acc[6][1] += av1.z * bv.y; acc[6][2] += av1.z * bv.z; acc[6][3] += av1.z * bv.w;
      acc[7][0] += av1.w * bv.x; acc[7][1] += av1.w * bv.y; acc[7][2] += av1.w * bv.z; acc[7][3] += av1.w * bv.w;
    }
    __syncthreads();
  }
  int sec = col0 / 768;   // uniform per block (64 | 768)
  float* O = (sec == 0) ? Oq : ((sec == 1) ? Ok : Ov);
  int lc = col0 - sec * 768 + tx * 4;
  float4 bi = *(const float4*)&bias[col0 + tx * 4];
#pragma unroll
  for (int i = 0; i < 8; ++i) {
    int r = row0 + ty * 8 + i;
    float4 v;
    v.x = acc[i][0] + bi.x; v.y = acc[i][1] + bi.y;
    v.z = acc[i][2] + bi.z; v.w = acc[i][3] + bi.w;
    if (sec < 2) {  // elu(x)+1
      v.x = (v.x > 0.f) ? v.x + 1.f : expf(v.x);
      v.y = (v.y > 0.f) ? v.y + 1.f : expf(v.y);
      v.z = (v.z > 0.f) ? v.z + 1.f : expf(v.z);
      v.w = (v.w > 0.f) ? v.w + 1.f : expf(v.w);
    }
    *(float4*)&O[(size_t)r * 768 + lc] = v;
  }
}

// ---------------- fp32 tiled GEMM 64x64, 256 thr, 4x4 (r7-proven) ----------------
// MODE 1: silu -> O0 (stride N).  MODE 2: +bias -> O0 (stride N).
template <int MODE>
__global__ __launch_bounds__(256) void gemm_fast(const float* __restrict__ A,
                                                 const float* __restrict__ Bm,
                                                 const float* __restrict__ bias,
                                                 float* __restrict__ O0,
                                                 int N, int K) {
  __shared__ float As[16][68];
  __shared__ float Bs[16][68];
  int tid = threadIdx.x;
  int tx = tid & 15, ty = tid >> 4;
  int row0 = blockIdx.y * 64, col0 = blockIdx.x * 64;
  float acc[4][4] = {};
  int ar = tid >> 2, ak = (tid & 3) * 4;
  int bk = tid >> 4, bc = (tid & 15) * 4;
  for (int k0 = 0; k0 < K; k0 += 16) {
    float4 a4 = *(const float4*)&A[(size_t)(row0 + ar) * K + k0 + ak];
    As[ak + 0][ar] = a4.x; As[ak + 1][ar] = a4.y;
    As[ak + 2][ar] = a4.z; As[ak + 3][ar] = a4.w;
    *(float4*)&Bs[bk][bc] = *(const float4*)&Bm[(size_t)(k0 + bk) * N + col0 + bc];
    __syncthreads();
#pragma unroll
    for (int kk = 0; kk < 16; ++kk) {
      float4 av = *(float4*)&As[kk][ty * 4];
      float4 bv = *(float4*)&Bs[kk][tx * 4];
      acc[0][0] += av.x * bv.x; acc[0][1] += av.x * bv.y; acc[0][2] += av.x * bv.z; acc[0][3] += av.x * bv.w;
      acc[1][0] += av.y * bv.x; acc[1][1] += av.y * bv.y; acc[1][2] += av.y * bv.z; acc[1][3] += av.y * bv.w;
      acc[2][0] += av.z * bv.x; acc[2][1] += av.z * bv.y; acc[2][2] += av.z * bv.z; acc[2][3] += av.z * bv.w;
      acc[3][0] += av.w * bv.x; acc[3][1] += av.w * bv.y; acc[3][2] += av.w * bv.z; acc[3][3] += av.w * bv.w;
    }
    __syncthreads();
  }
  if (MODE == 1) {
#pragma unroll
    for (int ii = 0; ii < 4; ++ii) {
      int r = row0 + ty * 4 + ii;
      float4 v;
      v.x = acc[ii][0]; v.y = acc[ii][1]; v.z = acc[ii][2]; v.w = acc[ii][3];
      v.x = v.x / (1.f + expf(-v.x));
      v.y = v.y / (1.f + expf(-v.y));
      v.z = v.z / (1.f + expf(-v.z));
      v.w = v.w / (1.f + expf(-v.w));
      *(float4*)&O0[(size_t)r * N + col0 + tx * 4] = v;
    }
  } else {
    float b0 = bias[col0 + tx * 4 + 0], b1 = bias[col0 + tx * 4 + 1];
    float b2 = bias[col0 + tx * 4 + 2], b3 = bias[col0 + tx * 4 + 3];
#pragma unroll
    for (int ii = 0; ii < 4; ++ii) {
      int r = row0 + ty * 4 + ii;
      float4 v;
      v.x = acc[ii][0] + b0; v.y = acc[ii][1] + b1;
      v.z = acc[ii][2] + b2; v.w = acc[ii][3] + b3;
      *(float4*)&O0[(size_t)r * N + col0 + tx * 4] = v;
    }
  }
}

// ---------------- params: h1 @ W_b2 -> gate / decay coefficients ----------------
__global__ __launch_bounds__(64) void params_kernel(const float* __restrict__ h1,
                                                    const float* __restrict__ Wb2,
                                                    const float* __restrict__ temp_p,
                                                    float* __restrict__ gate_out,
                                                    float* __restrict__ cg,
                                                    float* __restrict__ ce,
                                                    float* __restrict__ ld) {
  int t = blockIdx.x;
  int tid = threadIdx.x;
  __shared__ float hs[128];
  __shared__ float ps[60];
  *(float2*)&hs[tid * 2] = *(const float2*)&h1[(size_t)t * 128 + tid * 2];
  __syncthreads();
  if (tid < 60) {
    float acc = 0.f;
#pragma unroll 4
    for (int k = 0; k < 128; ++k) acc += hs[k] * Wb2[k * 60 + tid];
    ps[tid] = acc;
  }
  __syncthreads();
  if (tid < 12) {
    float p0 = ps[tid * 5 + 0], p1 = ps[tid * 5 + 1], p2 = ps[tid * 5 + 2];
    float p3 = ps[tid * 5 + 3], p4 = ps[tid * 5 + 4];
    float sa = 1.f / (1.f + expf(-p0));
    float sp = tanhf(p1) * PI_F;
    float ca = 1.f / (1.f + expf(-p2));
    float cp = tanhf(p3) * PI_F;
    float dec = 0.5f + 0.49f / (1.f + expf(-p4));
    float tmp = fminf(fmaxf(temp_p[0], 0.1f), 2.0f);
    float inter = tanhf(sa * ca * cosf(sp - cp)) * tmp;
    float gate = 1.f / (1.f + expf(-inter));
    gate_out[t * 12 + tid] = gate;
    int b = t >> 9, l = t & 511;
    int bhl = (b * 12 + tid) * L_ + l;
    float ema = 1.f - dec;
    cg[bhl] = ema * (1.f + gate);
    ce[bhl] = ema;
    ld[bhl] = logf(dec + 1e-8f);
  }
}

// ---------------- cumulative log-decay + chunk-end values ----------------
__global__ __launch_bounds__(64) void cld_kernel(const float* __restrict__ ld,
                                                 float* __restrict__ cld,
                                                 float* __restrict__ cEnd) {
  int bh = blockIdx.x;
  int lane = threadIdx.x;
  const float* src = ld + (size_t)bh * L_;
  float v[8];
  float s = 0.f;
#pragma unroll
  for (int i = 0; i < 8; ++i) { v[i] = src[lane * 8 + i]; s += v[i]; }
  float tot = s;
#pragma unroll
  for (int off = 1; off < 64; off <<= 1) {
    float n = __shfl_up(tot, off);
    if (lane >= off) tot += n;
  }
  float run = tot - s;
  float out7 = 0.f;
#pragma unroll
  for (int i = 0; i < 8; ++i) {
    run += v[i];
    float o = fmaxf(run, -85.f);
    cld[(size_t)bh * L_ + lane * 8 + i] = o;
    out7 = o;
  }
  if ((lane & 7) == 7) cEnd[bh * NC_ + (lane >> 3)] = out7;
}

// ---------------- overflow scan: exact fp32 mirror of ref's z cumsum ----------------
__global__ __launch_bounds__(64) void infscan_kernel(const float* __restrict__ kf,
                                                     const float* __restrict__ ce,
                                                     const float* __restrict__ cld,
                                                     int* __restrict__ tstar) {
  int bh = blockIdx.x;
  int b = bh / H_, h = bh - b * H_;
  int e = threadIdx.x;
  float cz = 0.f;
  int tf = L_;
  for (int t = 0; t < L_; ++t) {
    int idx = bh * L_ + t;
    float s = ce[idx] * expf(-cld[idx]);
    float kv = kf[(size_t)(b * L_ + t) * D_ + h * DH_ + e];
    cz = cz + kv * s;
    if (tf == L_ && isinf(cz)) tf = t;
  }
#pragma unroll
  for (int off = 1; off < 64; off <<= 1) tf = min(tf, __shfl_xor(tf, off));
  if (e == 0) tstar[bh] = tf;
}

// ---------------- per-chunk summaries T_c (64x64) and z_c (64) ----------------
__global__ __launch_bounds__(256) void chunk_sum_kernel(const float* __restrict__ kf,
                                                        const float* __restrict__ vf,
                                                        const float* __restrict__ cg,
                                                        const float* __restrict__ ce,
                                                        const float* __restrict__ cld,
                                                        const float* __restrict__ cEnd,
                                                        float* __restrict__ T,
                                                        float* __restrict__ zc) {
  int blk = blockIdx.x;
  int c = blk & 7, bh = blk >> 3;
  int b = bh / H_, h = bh - b * H_;
  int tid = threadIdx.x;
  __shared__ float kfs[64][68];
  __shared__ float vfs[64][68];
  __shared__ float wv[64], wz[64];
  float cend = cEnd[blk];
  if (tid < 64) {
    int idx = bh * L_ + c * 64 + tid;
    float w = expf(cend - cld[idx]);
    wv[tid] = cg[idx] * w;
    wz[tid] = ce[idx] * w;
  }
  __syncthreads();
  int t = tid >> 2, g4 = (tid & 3) * 16;
  size_t rowb = (size_t)(b * L_ + c * 64 + t) * D_ + h * 64 + g4;
  float wvt = wv[t];
#pragma unroll
  for (int i = 0; i < 4; ++i) {
    *(float4*)&kfs[t][g4 + 4 * i] = *(const float4*)&kf[rowb + 4 * i];
    float4 vv = *(const float4*)&vf[rowb + 4 * i];
    vv.x *= wvt; vv.y *= wvt; vv.z *= wvt; vv.w *= wvt;
    *(float4*)&vfs[t][g4 + 4 * i] = vv;
  }
  __syncthreads();
  int d = tid >> 2, eb = (tid & 3) * 16;
  float4 a0 = {}, a1 = {}, a2 = {}, a3 = {};
  for (int tt = 0; tt < 64; ++tt) {
    float kd = kfs[tt][d];
    float4 x0 = *(float4*)&vfs[tt][eb + 0];
    float4 x1 = *(float4*)&vfs[tt][eb + 4];
    float4 x2 = *(float4*)&vfs[tt][eb + 8];
    float4 x3 = *(float4*)&vfs[tt][eb + 12];
    a0.x += kd * x0.x; a0.y += kd * x0.y; a0.z += kd * x0.z; a0.w += kd * x0.w;
    a1.x += kd * x1.x; a1.y += kd * x1.y; a1.z += kd * x1.z; a1.w += kd * x1.w;
    a2.x += kd * x2.x; a2.y += kd * x2.y; a2.z += kd * x2.z; a2.w += kd * x2.w;
    a3.x += kd * x3.x; a3.y += kd * x3.y; a3.z += kd * x3.z; a3.w += kd * x3.w;
  }
  size_t tb = (size_t)blk * 4096 + (size_t)d * 64 + eb;
  *(float4*)&T[tb + 0] = a0;
  *(float4*)&T[tb + 4] = a1;
  *(float4*)&T[tb + 8] = a2;
  *(float4*)&T[tb + 12] = a3;
  if (tid < 64) {
    float za = 0.f;
#pragma unroll 8
    for (int tt = 0; tt < 64; ++tt) za += kfs[tt][tid] * wz[tt];
    zc[blk * 64 + tid] = za;
  }
}

// ---------------- inter-chunk scan (IN-PLACE: Sprev aliases T) ----------------
__global__ __launch_bounds__(256) void scan_kernel(float* __restrict__ T,
                                                   const float* __restrict__ zc,
                                                   const float* __restrict__ cEnd,
                                                   float* __restrict__ zprev) {
  int bh = blockIdx.x, tid = threadIdx.x;
  float4 s0 = {}, s1 = {}, s2 = {}, s3 = {};
  float zs = 0.f;
  float prevEnd = 0.f;
  for (int c = 0; c < NC_; ++c) {
    int blk = bh * NC_ + c;
    float r = expf(cEnd[blk] - prevEnd);
    prevEnd = cEnd[blk];
    size_t base = (size_t)blk * 4096 + (size_t)tid * 16;
    float4 t0 = *(const float4*)&T[base + 0];
    float4 t1 = *(const float4*)&T[base + 4];
    float4 t2 = *(const float4*)&T[base + 8];
    float4 t3 = *(const float4*)&T[base + 12];
    *(float4*)&T[base + 0] = s0;
    *(float4*)&T[base + 4] = s1;
    *(float4*)&T[base + 8] = s2;
    *(float4*)&T[base + 12] = s3;
    s0.x = s0.x * r + t0.x; s0.y = s0.y * r + t0.y; s0.z = s0.z * r + t0.z; s0.w = s0.w * r + t0.w;
    s1.x = s1.x * r + t1.x; s1.y = s1.y * r + t1.y; s1.z = s1.z * r + t1.z; s1.w = s1.w * r + t1.w;
    s2.x = s2.x * r + t2.x; s2.y = s2.y * r + t2.y; s2.z = s2.z * r + t2.z; s2.w = s2.w * r + t2.w;
    s3.x = s3.x * r + t3.x; s3.y = s3.y * r + t3.y; s3.z = s3.z * r + t3.z; s3.w = s3.w * r + t3.w;
    if (tid < 64) {
      zprev[blk * 64 + tid] = zs;
      zs = zs * r + zc[blk * 64 + tid];
    }
  }
}

// ---------------- per-chunk outputs (+ overflow mask), /den, LayerNorm(DH) ----------------
__global__ __launch_bounds__(256) void chunk_out_kernel(const float* __restrict__ qf,
                                                        const float* __restrict__ kf,
                                                        const float* __restrict__ vf,
                                                        const float* __restrict__ cg,
                                                        const float* __restrict__ ce,
                                                        const float* __restrict__ cld,
                                                        const float* __restrict__ cEnd,
                                                        const float* __restrict__ Sprev,
                                                        const float* __restrict__ zprev,
                                                        const int* __restrict__ tstar,
                                                        const float* __restrict__ mg,
                                                        const float* __restrict__ mb,
                                                        float* __restrict__ attn) {
  int blk = blockIdx.x;
  int c = blk & 7, bh = blk >> 3;
  int b = bh / H_, h = bh - b * H_;
  int tid = threadIdx.x;
  __shared__ float qfs[64][68];
  __shared__ float kfs[64][68];  // reused to hold M after score phase
  __shared__ float vfs[64][68];
  __shared__ float cldS[64], cgS[64], ceS[64], zS[64];
  int t = tid >> 2, g4 = (tid & 3) * 16;
  size_t rowb = (size_t)(b * L_ + c * 64 + t) * D_ + h * 64 + g4;
#pragma unroll
  for (int i = 0; i < 4; ++i) {
    *(float4*)&qfs[t][g4 + 4 * i] = *(const float4*)&qf[rowb + 4 * i];
    *(float4*)&kfs[t][g4 + 4 * i] = *(const float4*)&kf[rowb + 4 * i];
    *(float4*)&vfs[t][g4 + 4 * i] = *(const float4*)&vf[rowb + 4 * i];
  }
  if (tid < 64) {
    int idx = bh * L_ + c * 64 + tid;
    cldS[tid] = cld[idx];
    cgS[tid] = cg[idx];
    ceS[tid] = ce[idx];
    zS[tid] = zprev[blk * 64 + tid];
  }
  __syncthreads();
  float prevEnd = (c == 0) ? 0.f : cEnd[blk - 1];
  int ts = tstar[bh];
  int i = tid >> 2, jb = (tid & 3) * 16;
  float sc[16];
#pragma unroll
  for (int jj = 0; jj < 16; ++jj) sc[jj] = 0.f;
  for (int d = 0; d < 64; d += 4) {
    float4 q4 = *(float4*)&qfs[i][d];
#pragma unroll
    for (int jj = 0; jj < 16; ++jj) {
      float4 k4 = *(float4*)&kfs[jb + jj][d];
      sc[jj] += q4.x * k4.x + q4.y * k4.y + q4.z * k4.z + q4.w * k4.w;
    }
  }
  float cldi = cldS[i];
  float den = 0.f;
  float mvals[16];
#pragma unroll
  for (int jj = 0; jj < 16; ++jj) {
    int j = jb + jj;
    float w = (j <= i) ? expf(cldi - cldS[j]) : 0.f;
    float sw = sc[jj] * w;
    den += sw * ceS[j];
    mvals[jj] = sw * cgS[j];
  }
  float dz = 0.f;
#pragma unroll
  for (int dd = 0; dd < 16; ++dd) dz += qfs[i][jb + dd] * zS[jb + dd];
  den += __shfl_xor(den, 1); den += __shfl_xor(den, 2);
  dz += __shfl_xor(dz, 1);  dz += __shfl_xor(dz, 2);
  float wi = expf(cldi - prevEnd);
  den += wi * dz + 1e-6f;
  __syncthreads();
#pragma unroll
  for (int jj = 0; jj < 16; ++jj) kfs[i][jb + jj] = mvals[jj];
  __syncthreads();
  float4 o0 = {}, o1 = {}, o2 = {}, o3 = {};
  for (int j = 0; j < 64; ++j) {
    float m = kfs[i][j];
    float4 x0 = *(float4*)&vfs[j][jb + 0];
    float4 x1 = *(float4*)&vfs[j][jb + 4];
    float4 x2 = *(float4*)&vfs[j][jb + 8];
    float4 x3 = *(float4*)&vfs[j][jb + 12];
    o0.x += m * x0.x; o0.y += m * x0.y; o0.z += m * x0.z; o0.w += m * x0.w;
    o1.x += m * x1.x; o1.y += m * x1.y; o1.z += m * x1.z; o1.w += m * x1.w;
    o2.x += m * x2.x; o2.y += m * x2.y; o2.z += m * x2.z; o2.w += m * x2.w;
    o3.x += m * x3.x; o3.y += m * x3.y; o3.z += m * x3.z; o3.w += m * x3.w;
  }
  float4 p0 = {}, p1 = {}, p2 = {}, p3 = {};
  size_t sb = (size_t)blk * 4096;
  for (int d = 0; d < 64; ++d) {
    float qd = qfs[i][d];
    float4 x0 = *(const float4*)&Sprev[sb + d * 64 + jb + 0];
    float4 x1 = *(const float4*)&Sprev[sb + d * 64 + jb + 4];
    float4 x2 = *(const float4*)&Sprev[sb + d * 64 + jb + 8];
    float4 x3 = *(const float4*)&Sprev[sb + d * 64 + jb + 12];
    p0.x += qd * x0.x; p0.y += qd * x0.y; p0.z += qd * x0.z; p0.w += qd * x0.w;
    p1.x += qd * x1.x; p1.y += qd * x1.y; p1.z += qd * x1.z; p1.w += qd * x1.w;
    p2.x += qd * x2.x; p2.y += qd * x2.y; p2.z += qd * x2.z; p2.w += qd * x2.w;
    p3.x += qd * x3.x; p3.y += qd * x3.y; p3.z += qd * x3.z; p3.w += qd * x3.w;
  }
  size_t ob = (size_t)(b * L_ + c * 64 + i) * D_ + h * 64 + jb;
  if (c * 64 + i >= ts) {
#pragma unroll
    for (int q4i = 0; q4i < 4; ++q4i) {
      float4 w4;
      w4.x = mb[jb + q4i * 4 + 0]; w4.y = mb[jb + q4i * 4 + 1];
      w4.z = mb[jb + q4i * 4 + 2]; w4.w = mb[jb + q4i * 4 + 3];
      *(float4*)&attn[ob + q4i * 4] = w4;
    }
    return;
  }
  float inv = 1.0f / den;
  float o[16];
  o[0] = (o0.x + wi * p0.x) * inv;  o[1] = (o0.y + wi * p0.y) * inv;
  o[2] = (o0.z + wi * p0.z) * inv;  o[3] = (o0.w + wi * p0.w) * inv;
  o[4] = (o1.x + wi * p1.x) * inv;  o[5] = (o1.y + wi * p1.y) * inv;
  o[6] = (o1.z + wi * p1.z) * inv;  o[7] = (o1.w + wi * p1.w) * inv;
  o[8] = (o2.x + wi * p2.x) * inv;  o[9] = (o2.y + wi * p2.y) * inv;
  o[10] = (o2.z + wi * p2.z) * inv; o[11] = (o2.w + wi * p2.w) * inv;
  o[12] = (o3.x + wi * p3.x) * inv; o[13] = (o3.y + wi * p3.y) * inv;
  o[14] = (o3.z + wi * p3.z) * inv; o[15] = (o3.w + wi * p3.w) * inv;
  float s = 0.f, s2 = 0.f;
#pragma unroll
  for (int e2 = 0; e2 < 16; ++e2) { s += o[e2]; s2 += o[e2] * o[e2]; }
  s += __shfl_xor(s, 1);  s += __shfl_xor(s, 2);
  s2 += __shfl_xor(s2, 1); s2 += __shfl_xor(s2, 2);
  float mu = s * (1.f / 64.f);
  float var = s2 * (1.f / 64.f) - mu * mu;
  float rs = rsqrtf(var + 1e-5f);
#pragma unroll
  for (int q4i = 0; q4i < 4; ++q4i) {
    float4 w4;
    w4.x = (o[q4i * 4 + 0] - mu) * rs * mg[jb + q4i * 4 + 0] + mb[jb + q4i * 4 + 0];
    w4.y = (o[q4i * 4 + 1] - mu) * rs * mg[jb + q4i * 4 + 1] + mb[jb + q4i * 4 + 1];
    w4.z = (o[q4i * 4 + 2] - mu) * rs * mg[jb + q4i * 4 + 2] + mb[jb + q4i * 4 + 2];
    w4.w = (o[q4i * 4 + 3] - mu) * rs * mg[jb + q4i * 4 + 3] + mb[jb + q4i * 4 + 3];
    *(float4*)&attn[ob + q4i * 4] = w4;
  }
}

extern "C" void kernel_launch(void* const* d_in, const int* in_sizes, int n_in,
                              void* d_out, int out_size, void* d_ws, size_t ws_size,
                              hipStream_t stream) {
  const float* x     = (const float*)d_in[0];
  const float* Wqkv  = (const float*)d_in[1];
  const float* bqkv  = (const float*)d_in[2];
  const float* Wb1   = (const float*)d_in[3];
  const float* Wb2   = (const float*)d_in[4];
  const float* temp  = (const float*)d_in[5];
  const float* Wproj = (const float*)d_in[6];
  const float* bproj = (const float*)d_in[7];
  const float* lng   = (const float*)d_in[8];
  const float* lnb   = (const float*)d_in[9];
  const float* memg  = (const float*)d_in[10];
  const float* memb  = (const float*)d_in[11];
  float* out0 = (float*)d_out;
  float* gate = out0 + BLD_;

  static const int expect[12] = {1572864, 1769472, 2304, 98304, 7680, 1,
                                 589824, 768, 768, 768, 64, 64};
  int bad = (n_in == 12) ? -1 : 99;
  if (bad < 0) for (int i = 0; i < 12; ++i) if (in_sizes[i] != expect[i]) { bad = i; break; }
  size_t need = (size_t)(4 * BLD_ + 262144 + 4 * 24576) * sizeof(float);  // 26.61 MB (proven)
  if (bad >= 0) { sentinel_kernel<<<1, 1, 0, stream>>>(out0, 3.0e6f, (float)bad); return; }
  if (ws_size < need) { sentinel_kernel<<<1, 1, 0, stream>>>(out0, 1.0e6f, (float)(ws_size >> 20)); return; }

  float* ws   = (float*)d_ws;
  float* xn   = ws;                  // BLD_; holds murs (4096) until QKV, then T/Sprev
  float* qfb  = xn + BLD_;           // BLD_; reused as attn by chunk_out (same rows)
  float* kfb  = qfb + BLD_;
  float* vfb  = kfb + BLD_;
  float* h1   = vfb + BLD_;          // 262144; dead after params -> zc/zprev/cEnd/tstar
  float* cgb  = h1 + 262144;
  float* ceb  = cgb + 24576;
  float* ldb  = ceb + 24576;
  float* cldb = ldb + 24576;
  float* murs = xn;                  // 4096 floats; dead after QKV (T written later)
  float* Tb   = xn;                  // alias: T and (after in-place scan) Sprev
  float* zcb  = h1;
  float* zpv  = h1 + 24576;
  float* cEnd = h1 + 49152;          // 384
  int*   tstar = (int*)(h1 + 49536); // 48
  float* attn = qfb;                 // alias: chunk_out writes exactly the rows it read

  ln_stats<<<BL_, 256, 0, stream>>>(x, murs);
  gemm_fast<1><<<dim3(2, 32), 256, 0, stream>>>(x, Wb1, nullptr, h1, 128, 768);
  params_kernel<<<BL_, 64, 0, stream>>>(h1, Wb2, temp, gate, cgb, ceb, ldb);
  cld_kernel<<<BH_, 64, 0, stream>>>(ldb, cldb, cEnd);
  gemm_qkv<<<dim3(36, 32), 128, 0, stream>>>(x, murs, lng, lnb, Wqkv, bqkv, qfb, kfb, vfb);
  infscan_kernel<<<BH_, 64, 0, stream>>>(kfb, ceb, cldb, tstar);
  chunk_sum_kernel<<<BH_ * NC_, 256, 0, stream>>>(kfb, vfb, cgb, ceb, cldb, cEnd, Tb, zcb);
  scan_kernel<<<BH_, 256, 0, stream>>>(Tb, zcb, cEnd, zpv);
  chunk_out_kernel<<<BH_ * NC_, 256, 0, stream>>>(qfb, kfb, vfb, cgb, ceb, cldb, cEnd,
                                                  Tb, zpv, tstar, memg, memb, attn);
  gemm_fast<2><<<dim3(12, 32), 256, 0, stream>>>(attn, Wproj, bproj, out0, 768, 768);
}

// Round 10
// 416.355 us; speedup vs baseline: 1.1277x; 1.1213x over previous
//
#include <hip/hip_runtime.h>
#include <math.h>

#define PI_F 3.14159265358979323846f

static constexpr int L_ = 512, D_ = 768, H_ = 12, DH_ = 64;
static constexpr int BL_ = 2048;            // B*L
static constexpr int BLD_ = BL_ * D_;       // 1572864
static constexpr int NC_ = 8;               // chunks (512/64)
static constexpr int BH_ = 48;              // B*H

__global__ void sentinel_kernel(float* out, float code, float aux) {
  out[0] = code; out[1] = aux;
}

// ---------------- LN stats only: per-row mu, rs (normalization fused into QKV) ----
__global__ __launch_bounds__(256) void ln_stats(const float* __restrict__ x,
                                                float* __restrict__ murs) {
  int row = blockIdx.x, tid = threadIdx.x;
  const float* xr = x + (size_t)row * D_;
  float v0 = xr[tid], v1 = xr[tid + 256], v2 = xr[tid + 512];
  float s = v0 + v1 + v2;
  float s2 = v0 * v0 + v1 * v1 + v2 * v2;
#pragma unroll
  for (int off = 32; off > 0; off >>= 1) { s += __shfl_xor(s, off); s2 += __shfl_xor(s2, off); }
  __shared__ float red[8];
  if ((tid & 63) == 0) { red[tid >> 6] = s; red[4 + (tid >> 6)] = s2; }
  __syncthreads();
  if (tid == 0) {
    float st = red[0] + red[1] + red[2] + red[3];
    float qt = red[4] + red[5] + red[6] + red[7];
    float mu = st * (1.0f / D_);
    float var = qt * (1.0f / D_) - mu * mu;
    murs[2 * row] = mu;
    murs[2 * row + 1] = rsqrtf(var + 1e-5f);
  }
}

// ---------------- fused bottleneck: params = epilogue(silu(x@Wb1) @ Wb2) ------------
// One block per token; k-ascending fp32 accumulation (same order as the r7-passing
// gemm_fast<1> + params_kernel pair) so the decay/overflow boundary is preserved.
__global__ __launch_bounds__(128) void bottleneck_kernel(const float* __restrict__ x,
                                                         const float* __restrict__ Wb1,
                                                         const float* __restrict__ Wb2,
                                                         const float* __restrict__ temp_p,
                                                         float* __restrict__ gate_out,
                                                         float* __restrict__ cg,
                                                         float* __restrict__ ce,
                                                         float* __restrict__ ld) {
  int t = blockIdx.x;   // token 0..2047
  int tid = threadIdx.x;
  __shared__ float xs[768];
  __shared__ float hs[128];
  __shared__ float ps[60];
  const float* xr = x + (size_t)t * D_;
#pragma unroll
  for (int i = 0; i < 6; ++i) xs[tid + i * 128] = xr[tid + i * 128];
  __syncthreads();
  float acc = 0.f;
#pragma unroll 8
  for (int k = 0; k < 768; ++k) acc += xs[k] * Wb1[k * 128 + tid];
  hs[tid] = acc / (1.f + expf(-acc));   // silu
  __syncthreads();
  if (tid < 60) {
    float a = 0.f;
#pragma unroll 4
    for (int k = 0; k < 128; ++k) a += hs[k] * Wb2[k * 60 + tid];
    ps[tid] = a;
  }
  __syncthreads();
  if (tid < 12) {
    float p0 = ps[tid * 5 + 0], p1 = ps[tid * 5 + 1], p2 = ps[tid * 5 + 2];
    float p3 = ps[tid * 5 + 3], p4 = ps[tid * 5 + 4];
    float sa = 1.f / (1.f + expf(-p0));
    float sp = tanhf(p1) * PI_F;
    float ca = 1.f / (1.f + expf(-p2));
    float cp = tanhf(p3) * PI_F;
    float dec = 0.5f + 0.49f / (1.f + expf(-p4));
    float tmp = fminf(fmaxf(temp_p[0], 0.1f), 2.0f);
    float inter = tanhf(sa * ca * cosf(sp - cp)) * tmp;
    float gate = 1.f / (1.f + expf(-inter));
    gate_out[t * 12 + tid] = gate;
    int b = t >> 9, l = t & 511;
    int bhl = (b * 12 + tid) * L_ + l;
    float ema = 1.f - dec;
    cg[bhl] = ema * (1.f + gate);
    ce[bhl] = ema;
    ld[bhl] = logf(dec + 1e-8f);
  }
}

// ---------------- QKV GEMM: r7 geometry (64x64, 256 thr, 4x4) + fused LN ----------
__global__ __launch_bounds__(256) void gemm_qkv(const float* __restrict__ x,
                                                const float* __restrict__ murs,
                                                const float* __restrict__ lg,
                                                const float* __restrict__ lb,
                                                const float* __restrict__ Bm,
                                                const float* __restrict__ bias,
                                                float* __restrict__ Oq,
                                                float* __restrict__ Ok,
                                                float* __restrict__ Ov) {
  const int N = 2304, K = 768;
  __shared__ float As[16][68];
  __shared__ float Bs[16][68];
  int tid = threadIdx.x;
  int tx = tid & 15, ty = tid >> 4;
  int row0 = blockIdx.y * 64, col0 = blockIdx.x * 64;
  float acc[4][4] = {};
  int ar = tid >> 2, ak = (tid & 3) * 4;
  int bk = tid >> 4, bc = (tid & 15) * 4;
  float2 m2 = *(const float2*)&murs[2 * (row0 + ar)];
  float mu = m2.x, rs = m2.y;
  const float* Arow = x + (size_t)(row0 + ar) * K;
  for (int k0 = 0; k0 < K; k0 += 16) {
    float4 a4 = *(const float4*)&Arow[k0 + ak];
    float4 g4 = *(const float4*)&lg[k0 + ak];
    float4 c4 = *(const float4*)&lb[k0 + ak];
    a4.x = (a4.x - mu) * rs * g4.x + c4.x;
    a4.y = (a4.y - mu) * rs * g4.y + c4.y;
    a4.z = (a4.z - mu) * rs * g4.z + c4.z;
    a4.w = (a4.w - mu) * rs * g4.w + c4.w;
    As[ak + 0][ar] = a4.x; As[ak + 1][ar] = a4.y;
    As[ak + 2][ar] = a4.z; As[ak + 3][ar] = a4.w;
    *(float4*)&Bs[bk][bc] = *(const float4*)&Bm[(size_t)(k0 + bk) * N + col0 + bc];
    __syncthreads();
#pragma unroll
    for (int kk = 0; kk < 16; ++kk) {
      float4 av = *(float4*)&As[kk][ty * 4];
      float4 bv = *(float4*)&Bs[kk][tx * 4];
      acc[0][0] += av.x * bv.x; acc[0][1] += av.x * bv.y; acc[0][2] += av.x * bv.z; acc[0][3] += av.x * bv.w;
      acc[1][0] += av.y * bv.x; acc[1][1] += av.y * bv.y; acc[1][2] += av.y * bv.z; acc[1][3] += av.y * bv.w;
      acc[2][0] += av.z * bv.x; acc[2][1] += av.z * bv.y; acc[2][2] += av.z * bv.z; acc[2][3] += av.z * bv.w;
      acc[3][0] += av.w * bv.x; acc[3][1] += av.w * bv.y; acc[3][2] += av.w * bv.z; acc[3][3] += av.w * bv.w;
    }
    __syncthreads();
  }
  int sec = col0 / 768;   // uniform per block (64 | 768)
  float* O = (sec == 0) ? Oq : ((sec == 1) ? Ok : Ov);
  int lc = col0 - sec * 768 + tx * 4;
  float b0 = bias[col0 + tx * 4 + 0], b1 = bias[col0 + tx * 4 + 1];
  float b2 = bias[col0 + tx * 4 + 2], b3 = bias[col0 + tx * 4 + 3];
#pragma unroll
  for (int ii = 0; ii < 4; ++ii) {
    int r = row0 + ty * 4 + ii;
    float4 v;
    v.x = acc[ii][0] + b0; v.y = acc[ii][1] + b1;
    v.z = acc[ii][2] + b2; v.w = acc[ii][3] + b3;
    if (sec < 2) {  // elu(x)+1
      v.x = (v.x > 0.f) ? v.x + 1.f : expf(v.x);
      v.y = (v.y > 0.f) ? v.y + 1.f : expf(v.y);
      v.z = (v.z > 0.f) ? v.z + 1.f : expf(v.z);
      v.w = (v.w > 0.f) ? v.w + 1.f : expf(v.w);
    }
    *(float4*)&O[(size_t)r * 768 + lc] = v;
  }
}

// ---------------- fp32 tiled GEMM 64x64, 256 thr, 4x4 (r7-proven), +bias ----------
__global__ __launch_bounds__(256) void gemm_proj(const float* __restrict__ A,
                                                 const float* __restrict__ Bm,
                                                 const float* __restrict__ bias,
                                                 float* __restrict__ O0,
                                                 int N, int K) {
  __shared__ float As[16][68];
  __shared__ float Bs[16][68];
  int tid = threadIdx.x;
  int tx = tid & 15, ty = tid >> 4;
  int row0 = blockIdx.y * 64, col0 = blockIdx.x * 64;
  float acc[4][4] = {};
  int ar = tid >> 2, ak = (tid & 3) * 4;
  int bk = tid >> 4, bc = (tid & 15) * 4;
  for (int k0 = 0; k0 < K; k0 += 16) {
    float4 a4 = *(const float4*)&A[(size_t)(row0 + ar) * K + k0 + ak];
    As[ak + 0][ar] = a4.x; As[ak + 1][ar] = a4.y;
    As[ak + 2][ar] = a4.z; As[ak + 3][ar] = a4.w;
    *(float4*)&Bs[bk][bc] = *(const float4*)&Bm[(size_t)(k0 + bk) * N + col0 + bc];
    __syncthreads();
#pragma unroll
    for (int kk = 0; kk < 16; ++kk) {
      float4 av = *(float4*)&As[kk][ty * 4];
      float4 bv = *(float4*)&Bs[kk][tx * 4];
      acc[0][0] += av.x * bv.x; acc[0][1] += av.x * bv.y; acc[0][2] += av.x * bv.z; acc[0][3] += av.x * bv.w;
      acc[1][0] += av.y * bv.x; acc[1][1] += av.y * bv.y; acc[1][2] += av.y * bv.z; acc[1][3] += av.y * bv.w;
      acc[2][0] += av.z * bv.x; acc[2][1] += av.z * bv.y; acc[2][2] += av.z * bv.z; acc[2][3] += av.z * bv.w;
      acc[3][0] += av.w * bv.x; acc[3][1] += av.w * bv.y; acc[3][2] += av.w * bv.z; acc[3][3] += av.w * bv.w;
    }
    __syncthreads();
  }
  float b0 = bias[col0 + tx * 4 + 0], b1 = bias[col0 + tx * 4 + 1];
  float b2 = bias[col0 + tx * 4 + 2], b3 = bias[col0 + tx * 4 + 3];
#pragma unroll
  for (int ii = 0; ii < 4; ++ii) {
    int r = row0 + ty * 4 + ii;
    float4 v;
    v.x = acc[ii][0] + b0; v.y = acc[ii][1] + b1;
    v.z = acc[ii][2] + b2; v.w = acc[ii][3] + b3;
    *(float4*)&O0[(size_t)r * N + col0 + tx * 4] = v;
  }
}

// ---------------- cumulative log-decay + chunk-end values ----------------
__global__ __launch_bounds__(64) void cld_kernel(const float* __restrict__ ld,
                                                 float* __restrict__ cld,
                                                 float* __restrict__ cEnd) {
  int bh = blockIdx.x;
  int lane = threadIdx.x;
  const float* src = ld + (size_t)bh * L_;
  float v[8];
  float s = 0.f;
#pragma unroll
  for (int i = 0; i < 8; ++i) { v[i] = src[lane * 8 + i]; s += v[i]; }
  float tot = s;
#pragma unroll
  for (int off = 1; off < 64; off <<= 1) {
    float n = __shfl_up(tot, off);
    if (lane >= off) tot += n;
  }
  float run = tot - s;
  float out7 = 0.f;
#pragma unroll
  for (int i = 0; i < 8; ++i) {
    run += v[i];
    float o = fmaxf(run, -85.f);
    cld[(size_t)bh * L_ + lane * 8 + i] = o;
    out7 = o;
  }
  if ((lane & 7) == 7) cEnd[bh * NC_ + (lane >> 3)] = out7;
}

// ---------------- overflow scan: exact fp32 mirror of ref's z cumsum ----------------
__global__ __launch_bounds__(64) void infscan_kernel(const float* __restrict__ kf,
                                                     const float* __restrict__ ce,
                                                     const float* __restrict__ cld,
                                                     int* __restrict__ tstar) {
  int bh = blockIdx.x;
  int b = bh / H_, h = bh - b * H_;
  int e = threadIdx.x;
  float cz = 0.f;
  int tf = L_;
  for (int t = 0; t < L_; ++t) {
    int idx = bh * L_ + t;
    float s = ce[idx] * expf(-cld[idx]);
    float kv = kf[(size_t)(b * L_ + t) * D_ + h * DH_ + e];
    cz = cz + kv * s;
    if (tf == L_ && isinf(cz)) tf = t;
  }
#pragma unroll
  for (int off = 1; off < 64; off <<= 1) tf = min(tf, __shfl_xor(tf, off));
  if (e == 0) tstar[bh] = tf;
}

// ---------------- per-chunk summaries T_c (64x64) and z_c (64) ----------------
__global__ __launch_bounds__(256) void chunk_sum_kernel(const float* __restrict__ kf,
                                                        const float* __restrict__ vf,
                                                        const float* __restrict__ cg,
                                                        const float* __restrict__ ce,
                                                        const float* __restrict__ cld,
                                                        const float* __restrict__ cEnd,
                                                        float* __restrict__ T,
                                                        float* __restrict__ zc) {
  int blk = blockIdx.x;
  int c = blk & 7, bh = blk >> 3;
  int b = bh / H_, h = bh - b * H_;
  int tid = threadIdx.x;
  __shared__ float kfs[64][68];
  __shared__ float vfs[64][68];
  __shared__ float wv[64], wz[64];
  float cend = cEnd[blk];
  if (tid < 64) {
    int idx = bh * L_ + c * 64 + tid;
    float w = expf(cend - cld[idx]);
    wv[tid] = cg[idx] * w;
    wz[tid] = ce[idx] * w;
  }
  __syncthreads();
  int t = tid >> 2, g4 = (tid & 3) * 16;
  size_t rowb = (size_t)(b * L_ + c * 64 + t) * D_ + h * 64 + g4;
  float wvt = wv[t];
#pragma unroll
  for (int i = 0; i < 4; ++i) {
    *(float4*)&kfs[t][g4 + 4 * i] = *(const float4*)&kf[rowb + 4 * i];
    float4 vv = *(const float4*)&vf[rowb + 4 * i];
    vv.x *= wvt; vv.y *= wvt; vv.z *= wvt; vv.w *= wvt;
    *(float4*)&vfs[t][g4 + 4 * i] = vv;
  }
  __syncthreads();
  int d = tid >> 2, eb = (tid & 3) * 16;
  float4 a0 = {}, a1 = {}, a2 = {}, a3 = {};
  for (int tt = 0; tt < 64; ++tt) {
    float kd = kfs[tt][d];
    float4 x0 = *(float4*)&vfs[tt][eb + 0];
    float4 x1 = *(float4*)&vfs[tt][eb + 4];
    float4 x2 = *(float4*)&vfs[tt][eb + 8];
    float4 x3 = *(float4*)&vfs[tt][eb + 12];
    a0.x += kd * x0.x; a0.y += kd * x0.y; a0.z += kd * x0.z; a0.w += kd * x0.w;
    a1.x += kd * x1.x; a1.y += kd * x1.y; a1.z += kd * x1.z; a1.w += kd * x1.w;
    a2.x += kd * x2.x; a2.y += kd * x2.y; a2.z += kd * x2.z; a2.w += kd * x2.w;
    a3.x += kd * x3.x; a3.y += kd * x3.y; a3.z += kd * x3.z; a3.w += kd * x3.w;
  }
  size_t tb = (size_t)blk * 4096 + (size_t)d * 64 + eb;
  *(float4*)&T[tb + 0] = a0;
  *(float4*)&T[tb + 4] = a1;
  *(float4*)&T[tb + 8] = a2;
  *(float4*)&T[tb + 12] = a3;
  if (tid < 64) {
    float za = 0.f;
#pragma unroll 8
    for (int tt = 0; tt < 64; ++tt) za += kfs[tt][tid] * wz[tt];
    zc[blk * 64 + tid] = za;
  }
}

// ---------------- inter-chunk scan (IN-PLACE: Sprev aliases T) ----------------
__global__ __launch_bounds__(256) void scan_kernel(float* __restrict__ T,
                                                   const float* __restrict__ zc,
                                                   const float* __restrict__ cEnd,
                                                   float* __restrict__ zprev) {
  int bh = blockIdx.x, tid = threadIdx.x;
  float4 s0 = {}, s1 = {}, s2 = {}, s3 = {};
  float zs = 0.f;
  float prevEnd = 0.f;
  for (int c = 0; c < NC_; ++c) {
    int blk = bh * NC_ + c;
    float r = expf(cEnd[blk] - prevEnd);
    prevEnd = cEnd[blk];
    size_t base = (size_t)blk * 4096 + (size_t)tid * 16;
    float4 t0 = *(const float4*)&T[base + 0];
    float4 t1 = *(const float4*)&T[base + 4];
    float4 t2 = *(const float4*)&T[base + 8];
    float4 t3 = *(const float4*)&T[base + 12];
    *(float4*)&T[base + 0] = s0;
    *(float4*)&T[base + 4] = s1;
    *(float4*)&T[base + 8] = s2;
    *(float4*)&T[base + 12] = s3;
    s0.x = s0.x * r + t0.x; s0.y = s0.y * r + t0.y; s0.z = s0.z * r + t0.z; s0.w = s0.w * r + t0.w;
    s1.x = s1.x * r + t1.x; s1.y = s1.y * r + t1.y; s1.z = s1.z * r + t1.z; s1.w = s1.w * r + t1.w;
    s2.x = s2.x * r + t2.x; s2.y = s2.y * r + t2.y; s2.z = s2.z * r + t2.z; s2.w = s2.w * r + t2.w;
    s3.x = s3.x * r + t3.x; s3.y = s3.y * r + t3.y; s3.z = s3.z * r + t3.z; s3.w = s3.w * r + t3.w;
    if (tid < 64) {
      zprev[blk * 64 + tid] = zs;
      zs = zs * r + zc[blk * 64 + tid];
    }
  }
}

// ---------------- per-chunk outputs (+ overflow mask), /den, LayerNorm(DH) ----------------
__global__ __launch_bounds__(256) void chunk_out_kernel(const float* __restrict__ qf,
                                                        const float* __restrict__ kf,
                                                        const float* __restrict__ vf,
                                                        const float* __restrict__ cg,
                                                        const float* __restrict__ ce,
                                                        const float* __restrict__ cld,
                                                        const float* __restrict__ cEnd,
                                                        const float* __restrict__ Sprev,
                                                        const float* __restrict__ zprev,
                                                        const int* __restrict__ tstar,
                                                        const float* __restrict__ mg,
                                                        const float* __restrict__ mb,
                                                        float* __restrict__ attn) {
  int blk = blockIdx.x;
  int c = blk & 7, bh = blk >> 3;
  int b = bh / H_, h = bh - b * H_;
  int tid = threadIdx.x;
  __shared__ float qfs[64][68];
  __shared__ float kfs[64][68];  // reused to hold M after score phase
  __shared__ float vfs[64][68];
  __shared__ float cldS[64], cgS[64], ceS[64], zS[64];
  int t = tid >> 2, g4 = (tid & 3) * 16;
  size_t rowb = (size_t)(b * L_ + c * 64 + t) * D_ + h * 64 + g4;
#pragma unroll
  for (int i = 0; i < 4; ++i) {
    *(float4*)&qfs[t][g4 + 4 * i] = *(const float4*)&qf[rowb + 4 * i];
    *(float4*)&kfs[t][g4 + 4 * i] = *(const float4*)&kf[rowb + 4 * i];
    *(float4*)&vfs[t][g4 + 4 * i] = *(const float4*)&vf[rowb + 4 * i];
  }
  if (tid < 64) {
    int idx = bh * L_ + c * 64 + tid;
    cldS[tid] = cld[idx];
    cgS[tid] = cg[idx];
    ceS[tid] = ce[idx];
    zS[tid] = zprev[blk * 64 + tid];
  }
  __syncthreads();
  float prevEnd = (c == 0) ? 0.f : cEnd[blk - 1];
  int ts = tstar[bh];
  int i = tid >> 2, jb = (tid & 3) * 16;
  float sc[16];
#pragma unroll
  for (int jj = 0; jj < 16; ++jj) sc[jj] = 0.f;
  for (int d = 0; d < 64; d += 4) {
    float4 q4 = *(float4*)&qfs[i][d];
#pragma unroll
    for (int jj = 0; jj < 16; ++jj) {
      float4 k4 = *(float4*)&kfs[jb + jj][d];
      sc[jj] += q4.x * k4.x + q4.y * k4.y + q4.z * k4.z + q4.w * k4.w;
    }
  }
  float cldi = cldS[i];
  float den = 0.f;
  float mvals[16];
#pragma unroll
  for (int jj = 0; jj < 16; ++jj) {
    int j = jb + jj;
    float w = (j <= i) ? expf(cldi - cldS[j]) : 0.f;
    float sw = sc[jj] * w;
    den += sw * ceS[j];
    mvals[jj] = sw * cgS[j];
  }
  float dz = 0.f;
#pragma unroll
  for (int dd = 0; dd < 16; ++dd) dz += qfs[i][jb + dd] * zS[jb + dd];
  den += __shfl_xor(den, 1); den += __shfl_xor(den, 2);
  dz += __shfl_xor(dz, 1);  dz += __shfl_xor(dz, 2);
  float wi = expf(cldi - prevEnd);
  den += wi * dz + 1e-6f;
  __syncthreads();
#pragma unroll
  for (int jj = 0; jj < 16; ++jj) kfs[i][jb + jj] = mvals[jj];
  __syncthreads();
  float4 o0 = {}, o1 = {}, o2 = {}, o3 = {};
  for (int j = 0; j < 64; ++j) {
    float m = kfs[i][j];
    float4 x0 = *(float4*)&vfs[j][jb + 0];
    float4 x1 = *(float4*)&vfs[j][jb + 4];
    float4 x2 = *(float4*)&vfs[j][jb + 8];
    float4 x3 = *(float4*)&vfs[j][jb + 12];
    o0.x += m * x0.x; o0.y += m * x0.y; o0.z += m * x0.z; o0.w += m * x0.w;
    o1.x += m * x1.x; o1.y += m * x1.y; o1.z += m * x1.z; o1.w += m * x1.w;
    o2.x += m * x2.x; o2.y += m * x2.y; o2.z += m * x2.z; o2.w += m * x2.w;
    o3.x += m * x3.x; o3.y += m * x3.y; o3.z += m * x3.z; o3.w += m * x3.w;
  }
  float4 p0 = {}, p1 = {}, p2 = {}, p3 = {};
  size_t sb = (size_t)blk * 4096;
  for (int d = 0; d < 64; ++d) {
    float qd = qfs[i][d];
    float4 x0 = *(const float4*)&Sprev[sb + d * 64 + jb + 0];
    float4 x1 = *(const float4*)&Sprev[sb + d * 64 + jb + 4];
    float4 x2 = *(const float4*)&Sprev[sb + d * 64 + jb + 8];
    float4 x3 = *(const float4*)&Sprev[sb + d * 64 + jb + 12];
    p0.x += qd * x0.x; p0.y += qd * x0.y; p0.z += qd * x0.z; p0.w += qd * x0.w;
    p1.x += qd * x1.x; p1.y += qd * x1.y; p1.z += qd * x1.z; p1.w += qd * x1.w;
    p2.x += qd * x2.x; p2.y += qd * x2.y; p2.z += qd * x2.z; p2.w += qd * x2.w;
    p3.x += qd * x3.x; p3.y += qd * x3.y; p3.z += qd * x3.z; p3.w += qd * x3.w;
  }
  size_t ob = (size_t)(b * L_ + c * 64 + i) * D_ + h * 64 + jb;
  if (c * 64 + i >= ts) {
#pragma unroll
    for (int q4i = 0; q4i < 4; ++q4i) {
      float4 w4;
      w4.x = mb[jb + q4i * 4 + 0]; w4.y = mb[jb + q4i * 4 + 1];
      w4.z = mb[jb + q4i * 4 + 2]; w4.w = mb[jb + q4i * 4 + 3];
      *(float4*)&attn[ob + q4i * 4] = w4;
    }
    return;
  }
  float inv = 1.0f / den;
  float o[16];
  o[0] = (o0.x + wi * p0.x) * inv;  o[1] = (o0.y + wi * p0.y) * inv;
  o[2] = (o0.z + wi * p0.z) * inv;  o[3] = (o0.w + wi * p0.w) * inv;
  o[4] = (o1.x + wi * p1.x) * inv;  o[5] = (o1.y + wi * p1.y) * inv;
  o[6] = (o1.z + wi * p1.z) * inv;  o[7] = (o1.w + wi * p1.w) * inv;
  o[8] = (o2.x + wi * p2.x) * inv;  o[9] = (o2.y + wi * p2.y) * inv;
  o[10] = (o2.z + wi * p2.z) * inv; o[11] = (o2.w + wi * p2.w) * inv;
  o[12] = (o3.x + wi * p3.x) * inv; o[13] = (o3.y + wi * p3.y) * inv;
  o[14] = (o3.z + wi * p3.z) * inv; o[15] = (o3.w + wi * p3.w) * inv;
  float s = 0.f, s2 = 0.f;
#pragma unroll
  for (int e2 = 0; e2 < 16; ++e2) { s += o[e2]; s2 += o[e2] * o[e2]; }
  s += __shfl_xor(s, 1);  s += __shfl_xor(s, 2);
  s2 += __shfl_xor(s2, 1); s2 += __shfl_xor(s2, 2);
  float mu = s * (1.f / 64.f);
  float var = s2 * (1.f / 64.f) - mu * mu;
  float rs = rsqrtf(var + 1e-5f);
#pragma unroll
  for (int q4i = 0; q4i < 4; ++q4i) {
    float4 w4;
    w4.x = (o[q4i * 4 + 0] - mu) * rs * mg[jb + q4i * 4 + 0] + mb[jb + q4i * 4 + 0];
    w4.y = (o[q4i * 4 + 1] - mu) * rs * mg[jb + q4i * 4 + 1] + mb[jb + q4i * 4 + 1];
    w4.z = (o[q4i * 4 + 2] - mu) * rs * mg[jb + q4i * 4 + 2] + mb[jb + q4i * 4 + 2];
    w4.w = (o[q4i * 4 + 3] - mu) * rs * mg[jb + q4i * 4 + 3] + mb[jb + q4i * 4 + 3];
    *(float4*)&attn[ob + q4i * 4] = w4;
  }
}

extern "C" void kernel_launch(void* const* d_in, const int* in_sizes, int n_in,
                              void* d_out, int out_size, void* d_ws, size_t ws_size,
                              hipStream_t stream) {
  const float* x     = (const float*)d_in[0];
  const float* Wqkv  = (const float*)d_in[1];
  const float* bqkv  = (const float*)d_in[2];
  const float* Wb1   = (const float*)d_in[3];
  const float* Wb2   = (const float*)d_in[4];
  const float* temp  = (const float*)d_in[5];
  const float* Wproj = (const float*)d_in[6];
  const float* bproj = (const float*)d_in[7];
  const float* lng   = (const float*)d_in[8];
  const float* lnb   = (const float*)d_in[9];
  const float* memg  = (const float*)d_in[10];
  const float* memb  = (const float*)d_in[11];
  float* out0 = (float*)d_out;
  float* gate = out0 + BLD_;

  static const int expect[12] = {1572864, 1769472, 2304, 98304, 7680, 1,
                                 589824, 768, 768, 768, 64, 64};
  int bad = (n_in == 12) ? -1 : 99;
  if (bad < 0) for (int i = 0; i < 12; ++i) if (in_sizes[i] != expect[i]) { bad = i; break; }
  size_t need = (size_t)(4 * BLD_ + 262144 + 4 * 24576) * sizeof(float);  // 26.61 MB (proven)
  if (bad >= 0) { sentinel_kernel<<<1, 1, 0, stream>>>(out0, 3.0e6f, (float)bad); return; }
  if (ws_size < need) { sentinel_kernel<<<1, 1, 0, stream>>>(out0, 1.0e6f, (float)(ws_size >> 20)); return; }

  float* ws   = (float*)d_ws;
  float* xn   = ws;                  // BLD_; holds murs (4096) until QKV, then T/Sprev
  float* qfb  = xn + BLD_;           // BLD_; reused as attn by chunk_out (same rows)
  float* kfb  = qfb + BLD_;
  float* vfb  = kfb + BLD_;
  float* h1   = vfb + BLD_;          // 262144 scratch region -> zc/zprev/cEnd/tstar
  float* cgb  = h1 + 262144;
  float* ceb  = cgb + 24576;
  float* ldb  = ceb + 24576;
  float* cldb = ldb + 24576;
  float* murs = xn;                  // 4096 floats; dead after QKV (T written later)
  float* Tb   = xn;                  // alias: T and (after in-place scan) Sprev
  float* zcb  = h1;
  float* zpv  = h1 + 24576;
  float* cEnd = h1 + 49152;          // 384
  int*   tstar = (int*)(h1 + 49536); // 48
  float* attn = qfb;                 // alias: chunk_out writes exactly the rows it read

  ln_stats<<<BL_, 256, 0, stream>>>(x, murs);
  bottleneck_kernel<<<BL_, 128, 0, stream>>>(x, Wb1, Wb2, temp, gate, cgb, ceb, ldb);
  cld_kernel<<<BH_, 64, 0, stream>>>(ldb, cldb, cEnd);
  gemm_qkv<<<dim3(36, 32), 256, 0, stream>>>(x, murs, lng, lnb, Wqkv, bqkv, qfb, kfb, vfb);
  infscan_kernel<<<BH_, 64, 0, stream>>>(kfb, ceb, cldb, tstar);
  chunk_sum_kernel<<<BH_ * NC_, 256, 0, stream>>>(kfb, vfb, cgb, ceb, cldb, cEnd, Tb, zcb);
  scan_kernel<<<BH_, 256, 0, stream>>>(Tb, zcb, cEnd, zpv);
  chunk_out_kernel<<<BH_ * NC_, 256, 0, stream>>>(qfb, kfb, vfb, cgb, ceb, cldb, cEnd,
                                                  Tb, zpv, tstar, memg, memb, attn);
  gemm_proj<<<dim3(12, 32), 256, 0, stream>>>(attn, Wproj, bproj, out0, 768, 768);
}

// Round 11
// 399.542 us; speedup vs baseline: 1.1752x; 1.0421x over previous
//
#include <hip/hip_runtime.h>
#include <math.h>

#define PI_F 3.14159265358979323846f

static constexpr int L_ = 512, D_ = 768, H_ = 12, DH_ = 64;
static constexpr int BL_ = 2048;            // B*L
static constexpr int BLD_ = BL_ * D_;       // 1572864
static constexpr int NC_ = 8;               // chunks (512/64)
static constexpr int BH_ = 48;              // B*H

__global__ void sentinel_kernel(float* out, float code, float aux) {
  out[0] = code; out[1] = aux;
}

// ---------------- LN stats only: per-row mu, rs (normalization fused into QKV) ----
__global__ __launch_bounds__(256) void ln_stats(const float* __restrict__ x,
                                                float* __restrict__ murs) {
  int row = blockIdx.x, tid = threadIdx.x;
  const float* xr = x + (size_t)row * D_;
  float v0 = xr[tid], v1 = xr[tid + 256], v2 = xr[tid + 512];
  float s = v0 + v1 + v2;
  float s2 = v0 * v0 + v1 * v1 + v2 * v2;
#pragma unroll
  for (int off = 32; off > 0; off >>= 1) { s += __shfl_xor(s, off); s2 += __shfl_xor(s2, off); }
  __shared__ float red[8];
  if ((tid & 63) == 0) { red[tid >> 6] = s; red[4 + (tid >> 6)] = s2; }
  __syncthreads();
  if (tid == 0) {
    float st = red[0] + red[1] + red[2] + red[3];
    float qt = red[4] + red[5] + red[6] + red[7];
    float mu = st * (1.0f / D_);
    float var = qt * (1.0f / D_) - mu * mu;
    murs[2 * row] = mu;
    murs[2 * row + 1] = rsqrtf(var + 1e-5f);
  }
}

// ---------------- fused bottleneck: params = epilogue(silu(x@Wb1) @ Wb2) ------------
__global__ __launch_bounds__(128) void bottleneck_kernel(const float* __restrict__ x,
                                                         const float* __restrict__ Wb1,
                                                         const float* __restrict__ Wb2,
                                                         const float* __restrict__ temp_p,
                                                         float* __restrict__ gate_out,
                                                         float* __restrict__ cg,
                                                         float* __restrict__ ce,
                                                         float* __restrict__ ld) {
  int t = blockIdx.x;   // token 0..2047
  int tid = threadIdx.x;
  __shared__ float xs[768];
  __shared__ float hs[128];
  __shared__ float ps[60];
  const float* xr = x + (size_t)t * D_;
#pragma unroll
  for (int i = 0; i < 6; ++i) xs[tid + i * 128] = xr[tid + i * 128];
  __syncthreads();
  float acc = 0.f;
#pragma unroll 8
  for (int k = 0; k < 768; ++k) acc += xs[k] * Wb1[k * 128 + tid];
  hs[tid] = acc / (1.f + expf(-acc));   // silu
  __syncthreads();
  if (tid < 60) {
    float a = 0.f;
#pragma unroll 4
    for (int k = 0; k < 128; ++k) a += hs[k] * Wb2[k * 60 + tid];
    ps[tid] = a;
  }
  __syncthreads();
  if (tid < 12) {
    float p0 = ps[tid * 5 + 0], p1 = ps[tid * 5 + 1], p2 = ps[tid * 5 + 2];
    float p3 = ps[tid * 5 + 3], p4 = ps[tid * 5 + 4];
    float sa = 1.f / (1.f + expf(-p0));
    float sp = tanhf(p1) * PI_F;
    float ca = 1.f / (1.f + expf(-p2));
    float cp = tanhf(p3) * PI_F;
    float dec = 0.5f + 0.49f / (1.f + expf(-p4));
    float tmp = fminf(fmaxf(temp_p[0], 0.1f), 2.0f);
    float inter = tanhf(sa * ca * cosf(sp - cp)) * tmp;
    float gate = 1.f / (1.f + expf(-inter));
    gate_out[t * 12 + tid] = gate;
    int b = t >> 9, l = t & 511;
    int bhl = (b * 12 + tid) * L_ + l;
    float ema = 1.f - dec;
    cg[bhl] = ema * (1.f + gate);
    ce[bhl] = ema;
    ld[bhl] = logf(dec + 1e-8f);
  }
}

// ---------------- QKV GEMM: 64x64/4x4/256thr, BK=32, reg double-buffer, fused LN ---
__global__ __launch_bounds__(256) void gemm_qkv(const float* __restrict__ x,
                                                const float* __restrict__ murs,
                                                const float* __restrict__ lg,
                                                const float* __restrict__ lb,
                                                const float* __restrict__ Bm,
                                                const float* __restrict__ bias,
                                                float* __restrict__ Oq,
                                                float* __restrict__ Ok,
                                                float* __restrict__ Ov) {
  const int N = 2304, K = 768;
  __shared__ float As[32][68];
  __shared__ float Bs[32][68];
  int tid = threadIdx.x;
  int tx = tid & 15, ty = tid >> 4;
  int row0 = blockIdx.y * 64, col0 = blockIdx.x * 64;
  float acc[4][4] = {};
  int ar = tid >> 2, ak = (tid & 3) * 4;   // A: row ar, k-chunks ak and 16+ak (conflict-free)
  int bk = tid >> 4, bc = (tid & 15) * 4;  // B: k-rows bk and 16+bk
  float2 m2 = *(const float2*)&murs[2 * (row0 + ar)];
  float mu = m2.x, rs = m2.y;
  const float* Arow = x + (size_t)(row0 + ar) * K;
  float4 a0, a1, b0, b1;
  // prologue: load k-panel 0 (LN applied to A)
  {
    float4 r0 = *(const float4*)&Arow[ak];
    float4 r1 = *(const float4*)&Arow[16 + ak];
    float4 g0 = *(const float4*)&lg[ak],      c0 = *(const float4*)&lb[ak];
    float4 g1 = *(const float4*)&lg[16 + ak], c1 = *(const float4*)&lb[16 + ak];
    a0.x = (r0.x - mu) * rs * g0.x + c0.x; a0.y = (r0.y - mu) * rs * g0.y + c0.y;
    a0.z = (r0.z - mu) * rs * g0.z + c0.z; a0.w = (r0.w - mu) * rs * g0.w + c0.w;
    a1.x = (r1.x - mu) * rs * g1.x + c1.x; a1.y = (r1.y - mu) * rs * g1.y + c1.y;
    a1.z = (r1.z - mu) * rs * g1.z + c1.z; a1.w = (r1.w - mu) * rs * g1.w + c1.w;
    b0 = *(const float4*)&Bm[(size_t)bk * N + col0 + bc];
    b1 = *(const float4*)&Bm[(size_t)(16 + bk) * N + col0 + bc];
  }
  for (int k0 = 0; k0 < K; k0 += 32) {
    As[ak + 0][ar] = a0.x; As[ak + 1][ar] = a0.y;
    As[ak + 2][ar] = a0.z; As[ak + 3][ar] = a0.w;
    As[16 + ak + 0][ar] = a1.x; As[16 + ak + 1][ar] = a1.y;
    As[16 + ak + 2][ar] = a1.z; As[16 + ak + 3][ar] = a1.w;
    *(float4*)&Bs[bk][bc] = b0;
    *(float4*)&Bs[16 + bk][bc] = b1;
    __syncthreads();
    if (k0 + 32 < K) {  // prefetch next panel into regs; hides under FMA below
      int kn = k0 + 32;
      float4 r0 = *(const float4*)&Arow[kn + ak];
      float4 r1 = *(const float4*)&Arow[kn + 16 + ak];
      float4 g0 = *(const float4*)&lg[kn + ak],      c0 = *(const float4*)&lb[kn + ak];
      float4 g1 = *(const float4*)&lg[kn + 16 + ak], c1 = *(const float4*)&lb[kn + 16 + ak];
      a0.x = (r0.x - mu) * rs * g0.x + c0.x; a0.y = (r0.y - mu) * rs * g0.y + c0.y;
      a0.z = (r0.z - mu) * rs * g0.z + c0.z; a0.w = (r0.w - mu) * rs * g0.w + c0.w;
      a1.x = (r1.x - mu) * rs * g1.x + c1.x; a1.y = (r1.y - mu) * rs * g1.y + c1.y;
      a1.z = (r1.z - mu) * rs * g1.z + c1.z; a1.w = (r1.w - mu) * rs * g1.w + c1.w;
      b0 = *(const float4*)&Bm[(size_t)(kn + bk) * N + col0 + bc];
      b1 = *(const float4*)&Bm[(size_t)(kn + 16 + bk) * N + col0 + bc];
    }
#pragma unroll
    for (int kk = 0; kk < 32; ++kk) {
      float4 av = *(float4*)&As[kk][ty * 4];
      float4 bv = *(float4*)&Bs[kk][tx * 4];
      acc[0][0] += av.x * bv.x; acc[0][1] += av.x * bv.y; acc[0][2] += av.x * bv.z; acc[0][3] += av.x * bv.w;
      acc[1][0] += av.y * bv.x; acc[1][1] += av.y * bv.y; acc[1][2] += av.y * bv.z; acc[1][3] += av.y * bv.w;
      acc[2][0] += av.z * bv.x; acc[2][1] += av.z * bv.y; acc[2][2] += av.z * bv.z; acc[2][3] += av.z * bv.w;
      acc[3][0] += av.w * bv.x; acc[3][1] += av.w * bv.y; acc[3][2] += av.w * bv.z; acc[3][3] += av.w * bv.w;
    }
    __syncthreads();
  }
  int sec = col0 / 768;   // uniform per block (64 | 768)
  float* O = (sec == 0) ? Oq : ((sec == 1) ? Ok : Ov);
  int lc = col0 - sec * 768 + tx * 4;
  float b0s = bias[col0 + tx * 4 + 0], b1s = bias[col0 + tx * 4 + 1];
  float b2s = bias[col0 + tx * 4 + 2], b3s = bias[col0 + tx * 4 + 3];
#pragma unroll
  for (int ii = 0; ii < 4; ++ii) {
    int r = row0 + ty * 4 + ii;
    float4 v;
    v.x = acc[ii][0] + b0s; v.y = acc[ii][1] + b1s;
    v.z = acc[ii][2] + b2s; v.w = acc[ii][3] + b3s;
    if (sec < 2) {  // elu(x)+1
      v.x = (v.x > 0.f) ? v.x + 1.f : expf(v.x);
      v.y = (v.y > 0.f) ? v.y + 1.f : expf(v.y);
      v.z = (v.z > 0.f) ? v.z + 1.f : expf(v.z);
      v.w = (v.w > 0.f) ? v.w + 1.f : expf(v.w);
    }
    *(float4*)&O[(size_t)r * 768 + lc] = v;
  }
}

// ---------------- proj GEMM: same skeleton, no LN, +bias ----------------
__global__ __launch_bounds__(256) void gemm_proj(const float* __restrict__ A,
                                                 const float* __restrict__ Bm,
                                                 const float* __restrict__ bias,
                                                 float* __restrict__ O0,
                                                 int N, int K) {
  __shared__ float As[32][68];
  __shared__ float Bs[32][68];
  int tid = threadIdx.x;
  int tx = tid & 15, ty = tid >> 4;
  int row0 = blockIdx.y * 64, col0 = blockIdx.x * 64;
  float acc[4][4] = {};
  int ar = tid >> 2, ak = (tid & 3) * 4;
  int bk = tid >> 4, bc = (tid & 15) * 4;
  const float* Arow = A + (size_t)ar * K + (size_t)row0 * K;
  float4 a0, a1, b0, b1;
  a0 = *(const float4*)&Arow[ak];
  a1 = *(const float4*)&Arow[16 + ak];
  b0 = *(const float4*)&Bm[(size_t)bk * N + col0 + bc];
  b1 = *(const float4*)&Bm[(size_t)(16 + bk) * N + col0 + bc];
  for (int k0 = 0; k0 < K; k0 += 32) {
    As[ak + 0][ar] = a0.x; As[ak + 1][ar] = a0.y;
    As[ak + 2][ar] = a0.z; As[ak + 3][ar] = a0.w;
    As[16 + ak + 0][ar] = a1.x; As[16 + ak + 1][ar] = a1.y;
    As[16 + ak + 2][ar] = a1.z; As[16 + ak + 3][ar] = a1.w;
    *(float4*)&Bs[bk][bc] = b0;
    *(float4*)&Bs[16 + bk][bc] = b1;
    __syncthreads();
    if (k0 + 32 < K) {
      int kn = k0 + 32;
      a0 = *(const float4*)&Arow[kn + ak];
      a1 = *(const float4*)&Arow[kn + 16 + ak];
      b0 = *(const float4*)&Bm[(size_t)(kn + bk) * N + col0 + bc];
      b1 = *(const float4*)&Bm[(size_t)(kn + 16 + bk) * N + col0 + bc];
    }
#pragma unroll
    for (int kk = 0; kk < 32; ++kk) {
      float4 av = *(float4*)&As[kk][ty * 4];
      float4 bv = *(float4*)&Bs[kk][tx * 4];
      acc[0][0] += av.x * bv.x; acc[0][1] += av.x * bv.y; acc[0][2] += av.x * bv.z; acc[0][3] += av.x * bv.w;
      acc[1][0] += av.y * bv.x; acc[1][1] += av.y * bv.y; acc[1][2] += av.y * bv.z; acc[1][3] += av.y * bv.w;
      acc[2][0] += av.z * bv.x; acc[2][1] += av.z * bv.y; acc[2][2] += av.z * bv.z; acc[2][3] += av.z * bv.w;
      acc[3][0] += av.w * bv.x; acc[3][1] += av.w * bv.y; acc[3][2] += av.w * bv.z; acc[3][3] += av.w * bv.w;
    }
    __syncthreads();
  }
  float b0s = bias[col0 + tx * 4 + 0], b1s = bias[col0 + tx * 4 + 1];
  float b2s = bias[col0 + tx * 4 + 2], b3s = bias[col0 + tx * 4 + 3];
#pragma unroll
  for (int ii = 0; ii < 4; ++ii) {
    int r = row0 + ty * 4 + ii;
    float4 v;
    v.x = acc[ii][0] + b0s; v.y = acc[ii][1] + b1s;
    v.z = acc[ii][2] + b2s; v.w = acc[ii][3] + b3s;
    *(float4*)&O0[(size_t)r * N + col0 + tx * 4] = v;
  }
}

// ---------------- fused cld scan + overflow scan (one block per bh) ----------------
__global__ __launch_bounds__(64) void cldinf_kernel(const float* __restrict__ ld,
                                                    const float* __restrict__ ce,
                                                    const float* __restrict__ kf,
                                                    float* __restrict__ cld,
                                                    float* __restrict__ cEnd,
                                                    int* __restrict__ tstar) {
  int bh = blockIdx.x;
  int b = bh / H_, h = bh - b * H_;
  int lane = threadIdx.x;
  __shared__ float sArr[512];   // s_t = ce_t * exp(-cld_t), exact infscan operand
  const float* src = ld + (size_t)bh * L_;
  float v[8];
  float s = 0.f;
#pragma unroll
  for (int i = 0; i < 8; ++i) { v[i] = src[lane * 8 + i]; s += v[i]; }
  float tot = s;
#pragma unroll
  for (int off = 1; off < 64; off <<= 1) {
    float n = __shfl_up(tot, off);
    if (lane >= off) tot += n;
  }
  float run = tot - s;
  float out7 = 0.f;
#pragma unroll
  for (int i = 0; i < 8; ++i) {
    run += v[i];
    float o = fmaxf(run, -85.f);
    int idx = bh * L_ + lane * 8 + i;
    cld[idx] = o;
    sArr[lane * 8 + i] = ce[idx] * expf(-o);   // same expression as old infscan
    out7 = o;
  }
  if ((lane & 7) == 7) cEnd[bh * NC_ + (lane >> 3)] = out7;
  __syncthreads();
  // overflow scan: exact fp32 mirror of ref's z cumsum (t-ascending adds)
  float cz = 0.f;
  int tf = L_;
  const float* kcol = kf + (size_t)(b * L_) * D_ + h * DH_ + lane;
  for (int t = 0; t < L_; ++t) {
    float kv = kcol[(size_t)t * D_];
    cz = cz + kv * sArr[t];
    if (tf == L_ && isinf(cz)) tf = t;
  }
#pragma unroll
  for (int off = 1; off < 64; off <<= 1) tf = min(tf, __shfl_xor(tf, off));
  if (lane == 0) tstar[bh] = tf;
}

// ---------------- per-chunk summaries T_c (64x64) and z_c (64) ----------------
__global__ __launch_bounds__(256) void chunk_sum_kernel(const float* __restrict__ kf,
                                                        const float* __restrict__ vf,
                                                        const float* __restrict__ cg,
                                                        const float* __restrict__ ce,
                                                        const float* __restrict__ cld,
                                                        const float* __restrict__ cEnd,
                                                        float* __restrict__ T,
                                                        float* __restrict__ zc) {
  int blk = blockIdx.x;
  int c = blk & 7, bh = blk >> 3;
  int b = bh / H_, h = bh - b * H_;
  int tid = threadIdx.x;
  __shared__ float kfs[64][68];
  __shared__ float vfs[64][68];
  __shared__ float wv[64], wz[64];
  float cend = cEnd[blk];
  if (tid < 64) {
    int idx = bh * L_ + c * 64 + tid;
    float w = expf(cend - cld[idx]);
    wv[tid] = cg[idx] * w;
    wz[tid] = ce[idx] * w;
  }
  __syncthreads();
  int t = tid >> 2, g4 = (tid & 3) * 16;
  size_t rowb = (size_t)(b * L_ + c * 64 + t) * D_ + h * 64 + g4;
  float wvt = wv[t];
#pragma unroll
  for (int i = 0; i < 4; ++i) {
    *(float4*)&kfs[t][g4 + 4 * i] = *(const float4*)&kf[rowb + 4 * i];
    float4 vv = *(const float4*)&vf[rowb + 4 * i];
    vv.x *= wvt; vv.y *= wvt; vv.z *= wvt; vv.w *= wvt;
    *(float4*)&vfs[t][g4 + 4 * i] = vv;
  }
  __syncthreads();
  int d = tid >> 2, eb = (tid & 3) * 16;
  float4 a0 = {}, a1 = {}, a2 = {}, a3 = {};
  for (int tt = 0; tt < 64; ++tt) {
    float kd = kfs[tt][d];
    float4 x0 = *(float4*)&vfs[tt][eb + 0];
    float4 x1 = *(float4*)&vfs[tt][eb + 4];
    float4 x2 = *(float4*)&vfs[tt][eb + 8];
    float4 x3 = *(float4*)&vfs[tt][eb + 12];
    a0.x += kd * x0.x; a0.y += kd * x0.y; a0.z += kd * x0.z; a0.w += kd * x0.w;
    a1.x += kd * x1.x; a1.y += kd * x1.y; a1.z += kd * x1.z; a1.w += kd * x1.w;
    a2.x += kd * x2.x; a2.y += kd * x2.y; a2.z += kd * x2.z; a2.w += kd * x2.w;
    a3.x += kd * x3.x; a3.y += kd * x3.y; a3.z += kd * x3.z; a3.w += kd * x3.w;
  }
  size_t tb = (size_t)blk * 4096 + (size_t)d * 64 + eb;
  *(float4*)&T[tb + 0] = a0;
  *(float4*)&T[tb + 4] = a1;
  *(float4*)&T[tb + 8] = a2;
  *(float4*)&T[tb + 12] = a3;
  if (tid < 64) {
    float za = 0.f;
#pragma unroll 8
    for (int tt = 0; tt < 64; ++tt) za += kfs[tt][tid] * wz[tt];
    zc[blk * 64 + tid] = za;
  }
}

// ---------------- inter-chunk scan (IN-PLACE: Sprev aliases T) ----------------
__global__ __launch_bounds__(256) void scan_kernel(float* __restrict__ T,
                                                   const float* __restrict__ zc,
                                                   const float* __restrict__ cEnd,
                                                   float* __restrict__ zprev) {
  int bh = blockIdx.x, tid = threadIdx.x;
  float4 s0 = {}, s1 = {}, s2 = {}, s3 = {};
  float zs = 0.f;
  float prevEnd = 0.f;
  for (int c = 0; c < NC_; ++c) {
    int blk = bh * NC_ + c;
    float r = expf(cEnd[blk] - prevEnd);
    prevEnd = cEnd[blk];
    size_t base = (size_t)blk * 4096 + (size_t)tid * 16;
    float4 t0 = *(const float4*)&T[base + 0];
    float4 t1 = *(const float4*)&T[base + 4];
    float4 t2 = *(const float4*)&T[base + 8];
    float4 t3 = *(const float4*)&T[base + 12];
    *(float4*)&T[base + 0] = s0;
    *(float4*)&T[base + 4] = s1;
    *(float4*)&T[base + 8] = s2;
    *(float4*)&T[base + 12] = s3;
    s0.x = s0.x * r + t0.x; s0.y = s0.y * r + t0.y; s0.z = s0.z * r + t0.z; s0.w = s0.w * r + t0.w;
    s1.x = s1.x * r + t1.x; s1.y = s1.y * r + t1.y; s1.z = s1.z * r + t1.z; s1.w = s1.w * r + t1.w;
    s2.x = s2.x * r + t2.x; s2.y = s2.y * r + t2.y; s2.z = s2.z * r + t2.z; s2.w = s2.w * r + t2.w;
    s3.x = s3.x * r + t3.x; s3.y = s3.y * r + t3.y; s3.z = s3.z * r + t3.z; s3.w = s3.w * r + t3.w;
    if (tid < 64) {
      zprev[blk * 64 + tid] = zs;
      zs = zs * r + zc[blk * 64 + tid];
    }
  }
}

// ---------------- per-chunk outputs (+ overflow mask), /den, LayerNorm(DH) ----------------
__global__ __launch_bounds__(256) void chunk_out_kernel(const float* __restrict__ qf,
                                                        const float* __restrict__ kf,
                                                        const float* __restrict__ vf,
                                                        const float* __restrict__ cg,
                                                        const float* __restrict__ ce,
                                                        const float* __restrict__ cld,
                                                        const float* __restrict__ cEnd,
                                                        const float* __restrict__ Sprev,
                                                        const float* __restrict__ zprev,
                                                        const int* __restrict__ tstar,
                                                        const float* __restrict__ mg,
                                                        const float* __restrict__ mb,
                                                        float* __restrict__ attn) {
  int blk = blockIdx.x;
  int c = blk & 7, bh = blk >> 3;
  int b = bh / H_, h = bh - b * H_;
  int tid = threadIdx.x;
  __shared__ float qfs[64][68];
  __shared__ float kfs[64][68];  // reused to hold M after score phase
  __shared__ float vfs[64][68];
  __shared__ float cldS[64], cgS[64], ceS[64], zS[64];
  int t = tid >> 2, g4 = (tid & 3) * 16;
  size_t rowb = (size_t)(b * L_ + c * 64 + t) * D_ + h * 64 + g4;
#pragma unroll
  for (int i = 0; i < 4; ++i) {
    *(float4*)&qfs[t][g4 + 4 * i] = *(const float4*)&qf[rowb + 4 * i];
    *(float4*)&kfs[t][g4 + 4 * i] = *(const float4*)&kf[rowb + 4 * i];
    *(float4*)&vfs[t][g4 + 4 * i] = *(const float4*)&vf[rowb + 4 * i];
  }
  if (tid < 64) {
    int idx = bh * L_ + c * 64 + tid;
    cldS[tid] = cld[idx];
    cgS[tid] = cg[idx];
    ceS[tid] = ce[idx];
    zS[tid] = zprev[blk * 64 + tid];
  }
  __syncthreads();
  float prevEnd = (c == 0) ? 0.f : cEnd[blk - 1];
  int ts = tstar[bh];
  int i = tid >> 2, jb = (tid & 3) * 16;
  float sc[16];
#pragma unroll
  for (int jj = 0; jj < 16; ++jj) sc[jj] = 0.f;
  for (int d = 0; d < 64; d += 4) {
    float4 q4 = *(float4*)&qfs[i][d];
#pragma unroll
    for (int jj = 0; jj < 16; ++jj) {
      float4 k4 = *(float4*)&kfs[jb + jj][d];
      sc[jj] += q4.x * k4.x + q4.y * k4.y + q4.z * k4.z + q4.w * k4.w;
    }
  }
  float cldi = cldS[i];
  float den = 0.f;
  float mvals[16];
#pragma unroll
  for (int jj = 0; jj < 16; ++jj) {
    int j = jb + jj;
    float w = (j <= i) ? expf(cldi - cldS[j]) : 0.f;
    float sw = sc[jj] * w;
    den += sw * ceS[j];
    mvals[jj] = sw * cgS[j];
  }
  float dz = 0.f;
#pragma unroll
  for (int dd = 0; dd < 16; ++dd) dz += qfs[i][jb + dd] * zS[jb + dd];
  den += __shfl_xor(den, 1); den += __shfl_xor(den, 2);
  dz += __shfl_xor(dz, 1);  dz += __shfl_xor(dz, 2);
  float wi = expf(cldi - prevEnd);
  den += wi * dz + 1e-6f;
  __syncthreads();
#pragma unroll
  for (int jj = 0; jj < 16; ++jj) kfs[i][jb + jj] = mvals[jj];
  __syncthreads();
  float4 o0 = {}, o1 = {}, o2 = {}, o3 = {};
  for (int j = 0; j < 64; ++j) {
    float m = kfs[i][j];
    float4 x0 = *(float4*)&vfs[j][jb + 0];
    float4 x1 = *(float4*)&vfs[j][jb + 4];
    float4 x2 = *(float4*)&vfs[j][jb + 8];
    float4 x3 = *(float4*)&vfs[j][jb + 12];
    o0.x += m * x0.x; o0.y += m * x0.y; o0.z += m * x0.z; o0.w += m * x0.w;
    o1.x += m * x1.x; o1.y += m * x1.y; o1.z += m * x1.z; o1.w += m * x1.w;
    o2.x += m * x2.x; o2.y += m * x2.y; o2.z += m * x2.z; o2.w += m * x2.w;
    o3.x += m * x3.x; o3.y += m * x3.y; o3.z += m * x3.z; o3.w += m * x3.w;
  }
  float4 p0 = {}, p1 = {}, p2 = {}, p3 = {};
  size_t sb = (size_t)blk * 4096;
  for (int d = 0; d < 64; ++d) {
    float qd = qfs[i][d];
    float4 x0 = *(const float4*)&Sprev[sb + d * 64 + jb + 0];
    float4 x1 = *(const float4*)&Sprev[sb + d * 64 + jb + 4];
    float4 x2 = *(const float4*)&Sprev[sb + d * 64 + jb + 8];
    float4 x3 = *(const float4*)&Sprev[sb + d * 64 + jb + 12];
    p0.x += qd * x0.x; p0.y += qd * x0.y; p0.z += qd * x0.z; p0.w += qd * x0.w;
    p1.x += qd * x1.x; p1.y += qd * x1.y; p1.z += qd * x1.z; p1.w += qd * x1.w;
    p2.x += qd * x2.x; p2.y += qd * x2.y; p2.z += qd * x2.z; p2.w += qd * x2.w;
    p3.x += qd * x3.x; p3.y += qd * x3.y; p3.z += qd * x3.z; p3.w += qd * x3.w;
  }
  size_t ob = (size_t)(b * L_ + c * 64 + i) * D_ + h * 64 + jb;
  if (c * 64 + i >= ts) {
#pragma unroll
    for (int q4i = 0; q4i < 4; ++q4i) {
      float4 w4;
      w4.x = mb[jb + q4i * 4 + 0]; w4.y = mb[jb + q4i * 4 + 1];
      w4.z = mb[jb + q4i * 4 + 2]; w4.w = mb[jb + q4i * 4 + 3];
      *(float4*)&attn[ob + q4i * 4] = w4;
    }
    return;
  }
  float inv = 1.0f / den;
  float o[16];
  o[0] = (o0.x + wi * p0.x) * inv;  o[1] = (o0.y + wi * p0.y) * inv;
  o[2] = (o0.z + wi * p0.z) * inv;  o[3] = (o0.w + wi * p0.w) * inv;
  o[4] = (o1.x + wi * p1.x) * inv;  o[5] = (o1.y + wi * p1.y) * inv;
  o[6] = (o1.z + wi * p1.z) * inv;  o[7] = (o1.w + wi * p1.w) * inv;
  o[8] = (o2.x + wi * p2.x) * inv;  o[9] = (o2.y + wi * p2.y) * inv;
  o[10] = (o2.z + wi * p2.z) * inv; o[11] = (o2.w + wi * p2.w) * inv;
  o[12] = (o3.x + wi * p3.x) * inv; o[13] = (o3.y + wi * p3.y) * inv;
  o[14] = (o3.z + wi * p3.z) * inv; o[15] = (o3.w + wi * p3.w) * inv;
  float s = 0.f, s2 = 0.f;
#pragma unroll
  for (int e2 = 0; e2 < 16; ++e2) { s += o[e2]; s2 += o[e2] * o[e2]; }
  s += __shfl_xor(s, 1);  s += __shfl_xor(s, 2);
  s2 += __shfl_xor(s2, 1); s2 += __shfl_xor(s2, 2);
  float mu = s * (1.f / 64.f);
  float var = s2 * (1.f / 64.f) - mu * mu;
  float rs = rsqrtf(var + 1e-5f);
#pragma unroll
  for (int q4i = 0; q4i < 4; ++q4i) {
    float4 w4;
    w4.x = (o[q4i * 4 + 0] - mu) * rs * mg[jb + q4i * 4 + 0] + mb[jb + q4i * 4 + 0];
    w4.y = (o[q4i * 4 + 1] - mu) * rs * mg[jb + q4i * 4 + 1] + mb[jb + q4i * 4 + 1];
    w4.z = (o[q4i * 4 + 2] - mu) * rs * mg[jb + q4i * 4 + 2] + mb[jb + q4i * 4 + 2];
    w4.w = (o[q4i * 4 + 3] - mu) * rs * mg[jb + q4i * 4 + 3] + mb[jb + q4i * 4 + 3];
    *(float4*)&attn[ob + q4i * 4] = w4;
  }
}

extern "C" void kernel_launch(void* const* d_in, const int* in_sizes, int n_in,
                              void* d_out, int out_size, void* d_ws, size_t ws_size,
                              hipStream_t stream) {
  const float* x     = (const float*)d_in[0];
  const float* Wqkv  = (const float*)d_in[1];
  const float* bqkv  = (const float*)d_in[2];
  const float* Wb1   = (const float*)d_in[3];
  const float* Wb2   = (const float*)d_in[4];
  const float* temp  = (const float*)d_in[5];
  const float* Wproj = (const float*)d_in[6];
  const float* bproj = (const float*)d_in[7];
  const float* lng   = (const float*)d_in[8];
  const float* lnb   = (const float*)d_in[9];
  const float* memg  = (const float*)d_in[10];
  const float* memb  = (const float*)d_in[11];
  float* out0 = (float*)d_out;
  float* gate = out0 + BLD_;

  static const int expect[12] = {1572864, 1769472, 2304, 98304, 7680, 1,
                                 589824, 768, 768, 768, 64, 64};
  int bad = (n_in == 12) ? -1 : 99;
  if (bad < 0) for (int i = 0; i < 12; ++i) if (in_sizes[i] != expect[i]) { bad = i; break; }
  size_t need = (size_t)(4 * BLD_ + 262144 + 4 * 24576) * sizeof(float);  // 26.61 MB (proven)
  if (bad >= 0) { sentinel_kernel<<<1, 1, 0, stream>>>(out0, 3.0e6f, (float)bad); return; }
  if (ws_size < need) { sentinel_kernel<<<1, 1, 0, stream>>>(out0, 1.0e6f, (float)(ws_size >> 20)); return; }

  float* ws   = (float*)d_ws;
  float* xn   = ws;                  // BLD_; holds murs (4096) until QKV, then T/Sprev
  float* qfb  = xn + BLD_;           // BLD_; reused as attn by chunk_out (same rows)
  float* kfb  = qfb + BLD_;
  float* vfb  = kfb + BLD_;
  float* h1   = vfb + BLD_;          // 262144 scratch region -> zc/zprev/cEnd/tstar
  float* cgb  = h1 + 262144;
  float* ceb  = cgb + 24576;
  float* ldb  = ceb + 24576;
  float* cldb = ldb + 24576;
  float* murs = xn;                  // 4096 floats; dead after QKV (T written later)
  float* Tb   = xn;                  // alias: T and (after in-place scan) Sprev
  float* zcb  = h1;
  float* zpv  = h1 + 24576;
  float* cEnd = h1 + 49152;          // 384
  int*   tstar = (int*)(h1 + 49536); // 48
  float* attn = qfb;                 // alias: chunk_out writes exactly the rows it read

  ln_stats<<<BL_, 256, 0, stream>>>(x, murs);
  bottleneck_kernel<<<BL_, 128, 0, stream>>>(x, Wb1, Wb2, temp, gate, cgb, ceb, ldb);
  gemm_qkv<<<dim3(36, 32), 256, 0, stream>>>(x, murs, lng, lnb, Wqkv, bqkv, qfb, kfb, vfb);
  cldinf_kernel<<<BH_, 64, 0, stream>>>(ldb, ceb, kfb, cldb, cEnd, tstar);
  chunk_sum_kernel<<<BH_ * NC_, 256, 0, stream>>>(kfb, vfb, cgb, ceb, cldb, cEnd, Tb, zcb);
  scan_kernel<<<BH_, 256, 0, stream>>>(Tb, zcb, cEnd, zpv);
  chunk_out_kernel<<<BH_ * NC_, 256, 0, stream>>>(qfb, kfb, vfb, cgb, ceb, cldb, cEnd,
                                                  Tb, zpv, tstar, memg, memb, attn);
  gemm_proj<<<dim3(12, 32), 256, 0, stream>>>(attn, Wproj, bproj, out0, 768, 768);
}

// Round 12
// 383.859 us; speedup vs baseline: 1.2232x; 1.0409x over previous
//
#include <hip/hip_runtime.h>
#include <math.h>

#define PI_F 3.14159265358979323846f

static constexpr int L_ = 512, D_ = 768, H_ = 12, DH_ = 64;
static constexpr int BL_ = 2048;            // B*L
static constexpr int BLD_ = BL_ * D_;       // 1572864
static constexpr int NC_ = 8;               // chunks (512/64)
static constexpr int BH_ = 48;              // B*H

__global__ void sentinel_kernel(float* out, float code, float aux) {
  out[0] = code; out[1] = aux;
}

// ------- fused: LN stats (bit-identical to old ln_stats) + bottleneck MLP + params -
__global__ __launch_bounds__(256) void bottleneck_kernel(const float* __restrict__ x,
                                                         const float* __restrict__ Wb1,
                                                         const float* __restrict__ Wb2,
                                                         const float* __restrict__ temp_p,
                                                         float* __restrict__ murs,
                                                         float* __restrict__ gate_out,
                                                         float* __restrict__ cg,
                                                         float* __restrict__ ce,
                                                         float* __restrict__ ld) {
  int t = blockIdx.x;   // token 0..2047
  int tid = threadIdx.x;
  __shared__ float xs[768];
  __shared__ float hs[128];
  __shared__ float ps[60];
  __shared__ float red[8];
  const float* xr = x + (size_t)t * D_;
  // --- LN stats: identical loads + reduction order as the old ln_stats kernel ---
  float v0 = xr[tid], v1 = xr[tid + 256], v2 = xr[tid + 512];
  xs[tid] = v0; xs[tid + 256] = v1; xs[tid + 512] = v2;
  float s = v0 + v1 + v2;
  float s2 = v0 * v0 + v1 * v1 + v2 * v2;
#pragma unroll
  for (int off = 32; off > 0; off >>= 1) { s += __shfl_xor(s, off); s2 += __shfl_xor(s2, off); }
  if ((tid & 63) == 0) { red[tid >> 6] = s; red[4 + (tid >> 6)] = s2; }
  __syncthreads();
  if (tid == 0) {
    float st = red[0] + red[1] + red[2] + red[3];
    float qt = red[4] + red[5] + red[6] + red[7];
    float mu = st * (1.0f / D_);
    float var = qt * (1.0f / D_) - mu * mu;
    murs[2 * t] = mu;
    murs[2 * t + 1] = rsqrtf(var + 1e-5f);
  }
  // --- bottleneck h1 = silu(x @ Wb1): identical loop to r10 (threads 0..127) ---
  if (tid < 128) {
    float acc = 0.f;
#pragma unroll 8
    for (int k = 0; k < 768; ++k) acc += xs[k] * Wb1[k * 128 + tid];
    hs[tid] = acc / (1.f + expf(-acc));   // silu
  }
  __syncthreads();
  if (tid < 60) {
    float a = 0.f;
#pragma unroll 4
    for (int k = 0; k < 128; ++k) a += hs[k] * Wb2[k * 60 + tid];
    ps[tid] = a;
  }
  __syncthreads();
  if (tid < 12) {
    float p0 = ps[tid * 5 + 0], p1 = ps[tid * 5 + 1], p2 = ps[tid * 5 + 2];
    float p3 = ps[tid * 5 + 3], p4 = ps[tid * 5 + 4];
    float sa = 1.f / (1.f + expf(-p0));
    float sp = tanhf(p1) * PI_F;
    float ca = 1.f / (1.f + expf(-p2));
    float cp = tanhf(p3) * PI_F;
    float dec = 0.5f + 0.49f / (1.f + expf(-p4));
    float tmp = fminf(fmaxf(temp_p[0], 0.1f), 2.0f);
    float inter = tanhf(sa * ca * cosf(sp - cp)) * tmp;
    float gate = 1.f / (1.f + expf(-inter));
    gate_out[t * 12 + tid] = gate;
    int b = t >> 9, l = t & 511;
    int bhl = (b * 12 + tid) * L_ + l;
    float ema = 1.f - dec;
    cg[bhl] = ema * (1.f + gate);
    ce[bhl] = ema;
    ld[bhl] = logf(dec + 1e-8f);
  }
}

// ---------------- QKV GEMM: r10-proven (64x64, 256 thr, 4x4, BK=16) + fused LN ----
__global__ __launch_bounds__(256) void gemm_qkv(const float* __restrict__ x,
                                                const float* __restrict__ murs,
                                                const float* __restrict__ lg,
                                                const float* __restrict__ lb,
                                                const float* __restrict__ Bm,
                                                const float* __restrict__ bias,
                                                float* __restrict__ Oq,
                                                float* __restrict__ Ok,
                                                float* __restrict__ Ov) {
  const int N = 2304, K = 768;
  __shared__ float As[16][68];
  __shared__ float Bs[16][68];
  int tid = threadIdx.x;
  int tx = tid & 15, ty = tid >> 4;
  int row0 = blockIdx.y * 64, col0 = blockIdx.x * 64;
  float acc[4][4] = {};
  int ar = tid >> 2, ak = (tid & 3) * 4;
  int bk = tid >> 4, bc = (tid & 15) * 4;
  float2 m2 = *(const float2*)&murs[2 * (row0 + ar)];
  float mu = m2.x, rs = m2.y;
  const float* Arow = x + (size_t)(row0 + ar) * K;
  for (int k0 = 0; k0 < K; k0 += 16) {
    float4 a4 = *(const float4*)&Arow[k0 + ak];
    float4 g4 = *(const float4*)&lg[k0 + ak];
    float4 c4 = *(const float4*)&lb[k0 + ak];
    a4.x = (a4.x - mu) * rs * g4.x + c4.x;
    a4.y = (a4.y - mu) * rs * g4.y + c4.y;
    a4.z = (a4.z - mu) * rs * g4.z + c4.z;
    a4.w = (a4.w - mu) * rs * g4.w + c4.w;
    As[ak + 0][ar] = a4.x; As[ak + 1][ar] = a4.y;
    As[ak + 2][ar] = a4.z; As[ak + 3][ar] = a4.w;
    *(float4*)&Bs[bk][bc] = *(const float4*)&Bm[(size_t)(k0 + bk) * N + col0 + bc];
    __syncthreads();
#pragma unroll
    for (int kk = 0; kk < 16; ++kk) {
      float4 av = *(float4*)&As[kk][ty * 4];
      float4 bv = *(float4*)&Bs[kk][tx * 4];
      acc[0][0] += av.x * bv.x; acc[0][1] += av.x * bv.y; acc[0][2] += av.x * bv.z; acc[0][3] += av.x * bv.w;
      acc[1][0] += av.y * bv.x; acc[1][1] += av.y * bv.y; acc[1][2] += av.y * bv.z; acc[1][3] += av.y * bv.w;
      acc[2][0] += av.z * bv.x; acc[2][1] += av.z * bv.y; acc[2][2] += av.z * bv.z; acc[2][3] += av.z * bv.w;
      acc[3][0] += av.w * bv.x; acc[3][1] += av.w * bv.y; acc[3][2] += av.w * bv.z; acc[3][3] += av.w * bv.w;
    }
    __syncthreads();
  }
  int sec = col0 / 768;   // uniform per block (64 | 768)
  float* O = (sec == 0) ? Oq : ((sec == 1) ? Ok : Ov);
  int lc = col0 - sec * 768 + tx * 4;
  float b0 = bias[col0 + tx * 4 + 0], b1 = bias[col0 + tx * 4 + 1];
  float b2 = bias[col0 + tx * 4 + 2], b3 = bias[col0 + tx * 4 + 3];
#pragma unroll
  for (int ii = 0; ii < 4; ++ii) {
    int r = row0 + ty * 4 + ii;
    float4 v;
    v.x = acc[ii][0] + b0; v.y = acc[ii][1] + b1;
    v.z = acc[ii][2] + b2; v.w = acc[ii][3] + b3;
    if (sec < 2) {  // elu(x)+1
      v.x = (v.x > 0.f) ? v.x + 1.f : expf(v.x);
      v.y = (v.y > 0.f) ? v.y + 1.f : expf(v.y);
      v.z = (v.z > 0.f) ? v.z + 1.f : expf(v.z);
      v.w = (v.w > 0.f) ? v.w + 1.f : expf(v.w);
    }
    *(float4*)&O[(size_t)r * 768 + lc] = v;
  }
}

// ---------------- proj GEMM: r10-proven (64x64, 256 thr, 4x4, BK=16), +bias --------
__global__ __launch_bounds__(256) void gemm_proj(const float* __restrict__ A,
                                                 const float* __restrict__ Bm,
                                                 const float* __restrict__ bias,
                                                 float* __restrict__ O0,
                                                 int N, int K) {
  __shared__ float As[16][68];
  __shared__ float Bs[16][68];
  int tid = threadIdx.x;
  int tx = tid & 15, ty = tid >> 4;
  int row0 = blockIdx.y * 64, col0 = blockIdx.x * 64;
  float acc[4][4] = {};
  int ar = tid >> 2, ak = (tid & 3) * 4;
  int bk = tid >> 4, bc = (tid & 15) * 4;
  for (int k0 = 0; k0 < K; k0 += 16) {
    float4 a4 = *(const float4*)&A[(size_t)(row0 + ar) * K + k0 + ak];
    As[ak + 0][ar] = a4.x; As[ak + 1][ar] = a4.y;
    As[ak + 2][ar] = a4.z; As[ak + 3][ar] = a4.w;
    *(float4*)&Bs[bk][bc] = *(const float4*)&Bm[(size_t)(k0 + bk) * N + col0 + bc];
    __syncthreads();
#pragma unroll
    for (int kk = 0; kk < 16; ++kk) {
      float4 av = *(float4*)&As[kk][ty * 4];
      float4 bv = *(float4*)&Bs[kk][tx * 4];
      acc[0][0] += av.x * bv.x; acc[0][1] += av.x * bv.y; acc[0][2] += av.x * bv.z; acc[0][3] += av.x * bv.w;
      acc[1][0] += av.y * bv.x; acc[1][1] += av.y * bv.y; acc[1][2] += av.y * bv.z; acc[1][3] += av.y * bv.w;
      acc[2][0] += av.z * bv.x; acc[2][1] += av.z * bv.y; acc[2][2] += av.z * bv.z; acc[2][3] += av.z * bv.w;
      acc[3][0] += av.w * bv.x; acc[3][1] += av.w * bv.y; acc[3][2] += av.w * bv.z; acc[3][3] += av.w * bv.w;
    }
    __syncthreads();
  }
  float b0 = bias[col0 + tx * 4 + 0], b1 = bias[col0 + tx * 4 + 1];
  float b2 = bias[col0 + tx * 4 + 2], b3 = bias[col0 + tx * 4 + 3];
#pragma unroll
  for (int ii = 0; ii < 4; ++ii) {
    int r = row0 + ty * 4 + ii;
    float4 v;
    v.x = acc[ii][0] + b0; v.y = acc[ii][1] + b1;
    v.z = acc[ii][2] + b2; v.w = acc[ii][3] + b3;
    *(float4*)&O0[(size_t)r * N + col0 + tx * 4] = v;
  }
}

// ---------------- fused cld scan + overflow scan (r11-proven) ----------------
__global__ __launch_bounds__(64) void cldinf_kernel(const float* __restrict__ ld,
                                                    const float* __restrict__ ce,
                                                    const float* __restrict__ kf,
                                                    float* __restrict__ cld,
                                                    float* __restrict__ cEnd,
                                                    int* __restrict__ tstar) {
  int bh = blockIdx.x;
  int b = bh / H_, h = bh - b * H_;
  int lane = threadIdx.x;
  __shared__ float sArr[512];   // s_t = ce_t * exp(-cld_t), exact infscan operand
  const float* src = ld + (size_t)bh * L_;
  float v[8];
  float s = 0.f;
#pragma unroll
  for (int i = 0; i < 8; ++i) { v[i] = src[lane * 8 + i]; s += v[i]; }
  float tot = s;
#pragma unroll
  for (int off = 1; off < 64; off <<= 1) {
    float n = __shfl_up(tot, off);
    if (lane >= off) tot += n;
  }
  float run = tot - s;
  float out7 = 0.f;
#pragma unroll
  for (int i = 0; i < 8; ++i) {
    run += v[i];
    float o = fmaxf(run, -85.f);
    int idx = bh * L_ + lane * 8 + i;
    cld[idx] = o;
    sArr[lane * 8 + i] = ce[idx] * expf(-o);
    out7 = o;
  }
  if ((lane & 7) == 7) cEnd[bh * NC_ + (lane >> 3)] = out7;
  __syncthreads();
  float cz = 0.f;
  int tf = L_;
  const float* kcol = kf + (size_t)(b * L_) * D_ + h * DH_ + lane;
  for (int t = 0; t < L_; ++t) {
    float kv = kcol[(size_t)t * D_];
    cz = cz + kv * sArr[t];
    if (tf == L_ && isinf(cz)) tf = t;
  }
#pragma unroll
  for (int off = 1; off < 64; off <<= 1) tf = min(tf, __shfl_xor(tf, off));
  if (lane == 0) tstar[bh] = tf;
}

// ---------------- per-chunk summaries T_c (64x64) and z_c (64) ----------------
__global__ __launch_bounds__(256) void chunk_sum_kernel(const float* __restrict__ kf,
                                                        const float* __restrict__ vf,
                                                        const float* __restrict__ cg,
                                                        const float* __restrict__ ce,
                                                        const float* __restrict__ cld,
                                                        const float* __restrict__ cEnd,
                                                        float* __restrict__ T,
                                                        float* __restrict__ zc) {
  int blk = blockIdx.x;
  int c = blk & 7, bh = blk >> 3;
  int b = bh / H_, h = bh - b * H_;
  int tid = threadIdx.x;
  __shared__ float kfs[64][68];
  __shared__ float vfs[64][68];
  __shared__ float wv[64], wz[64];
  float cend = cEnd[blk];
  if (tid < 64) {
    int idx = bh * L_ + c * 64 + tid;
    float w = expf(cend - cld[idx]);
    wv[tid] = cg[idx] * w;
    wz[tid] = ce[idx] * w;
  }
  __syncthreads();
  int t = tid >> 2, g4 = (tid & 3) * 16;
  size_t rowb = (size_t)(b * L_ + c * 64 + t) * D_ + h * 64 + g4;
  float wvt = wv[t];
#pragma unroll
  for (int i = 0; i < 4; ++i) {
    *(float4*)&kfs[t][g4 + 4 * i] = *(const float4*)&kf[rowb + 4 * i];
    float4 vv = *(const float4*)&vf[rowb + 4 * i];
    vv.x *= wvt; vv.y *= wvt; vv.z *= wvt; vv.w *= wvt;
    *(float4*)&vfs[t][g4 + 4 * i] = vv;
  }
  __syncthreads();
  int d = tid >> 2, eb = (tid & 3) * 16;
  float4 a0 = {}, a1 = {}, a2 = {}, a3 = {};
  for (int tt = 0; tt < 64; ++tt) {
    float kd = kfs[tt][d];
    float4 x0 = *(float4*)&vfs[tt][eb + 0];
    float4 x1 = *(float4*)&vfs[tt][eb + 4];
    float4 x2 = *(float4*)&vfs[tt][eb + 8];
    float4 x3 = *(float4*)&vfs[tt][eb + 12];
    a0.x += kd * x0.x; a0.y += kd * x0.y; a0.z += kd * x0.z; a0.w += kd * x0.w;
    a1.x += kd * x1.x; a1.y += kd * x1.y; a1.z += kd * x1.z; a1.w += kd * x1.w;
    a2.x += kd * x2.x; a2.y += kd * x2.y; a2.z += kd * x2.z; a2.w += kd * x2.w;
    a3.x += kd * x3.x; a3.y += kd * x3.y; a3.z += kd * x3.z; a3.w += kd * x3.w;
  }
  size_t tb = (size_t)blk * 4096 + (size_t)d * 64 + eb;
  *(float4*)&T[tb + 0] = a0;
  *(float4*)&T[tb + 4] = a1;
  *(float4*)&T[tb + 8] = a2;
  *(float4*)&T[tb + 12] = a3;
  if (tid < 64) {
    float za = 0.f;
#pragma unroll 8
    for (int tt = 0; tt < 64; ++tt) za += kfs[tt][tid] * wz[tt];
    zc[blk * 64 + tid] = za;
  }
}

// ---------------- inter-chunk scan (IN-PLACE: Sprev aliases T) ----------------
__global__ __launch_bounds__(256) void scan_kernel(float* __restrict__ T,
                                                   const float* __restrict__ zc,
                                                   const float* __restrict__ cEnd,
                                                   float* __restrict__ zprev) {
  int bh = blockIdx.x, tid = threadIdx.x;
  float4 s0 = {}, s1 = {}, s2 = {}, s3 = {};
  float zs = 0.f;
  float prevEnd = 0.f;
  for (int c = 0; c < NC_; ++c) {
    int blk = bh * NC_ + c;
    float r = expf(cEnd[blk] - prevEnd);
    prevEnd = cEnd[blk];
    size_t base = (size_t)blk * 4096 + (size_t)tid * 16;
    float4 t0 = *(const float4*)&T[base + 0];
    float4 t1 = *(const float4*)&T[base + 4];
    float4 t2 = *(const float4*)&T[base + 8];
    float4 t3 = *(const float4*)&T[base + 12];
    *(float4*)&T[base + 0] = s0;
    *(float4*)&T[base + 4] = s1;
    *(float4*)&T[base + 8] = s2;
    *(float4*)&T[base + 12] = s3;
    s0.x = s0.x * r + t0.x; s0.y = s0.y * r + t0.y; s0.z = s0.z * r + t0.z; s0.w = s0.w * r + t0.w;
    s1.x = s1.x * r + t1.x; s1.y = s1.y * r + t1.y; s1.z = s1.z * r + t1.z; s1.w = s1.w * r + t1.w;
    s2.x = s2.x * r + t2.x; s2.y = s2.y * r + t2.y; s2.z = s2.z * r + t2.z; s2.w = s2.w * r + t2.w;
    s3.x = s3.x * r + t3.x; s3.y = s3.y * r + t3.y; s3.z = s3.z * r + t3.z; s3.w = s3.w * r + t3.w;
    if (tid < 64) {
      zprev[blk * 64 + tid] = zs;
      zs = zs * r + zc[blk * 64 + tid];
    }
  }
}

// ---------------- per-chunk outputs (+ overflow mask), /den, LayerNorm(DH) ----------------
__global__ __launch_bounds__(256) void chunk_out_kernel(const float* __restrict__ qf,
                                                        const float* __restrict__ kf,
                                                        const float* __restrict__ vf,
                                                        const float* __restrict__ cg,
                                                        const float* __restrict__ ce,
                                                        const float* __restrict__ cld,
                                                        const float* __restrict__ cEnd,
                                                        const float* __restrict__ Sprev,
                                                        const float* __restrict__ zprev,
                                                        const int* __restrict__ tstar,
                                                        const float* __restrict__ mg,
                                                        const float* __restrict__ mb,
                                                        float* __restrict__ attn) {
  int blk = blockIdx.x;
  int c = blk & 7, bh = blk >> 3;
  int b = bh / H_, h = bh - b * H_;
  int tid = threadIdx.x;
  __shared__ float qfs[64][68];
  __shared__ float kfs[64][68];  // reused to hold M after score phase
  __shared__ float vfs[64][68];
  __shared__ float cldS[64], cgS[64], ceS[64], zS[64];
  int t = tid >> 2, g4 = (tid & 3) * 16;
  size_t rowb = (size_t)(b * L_ + c * 64 + t) * D_ + h * 64 + g4;
#pragma unroll
  for (int i = 0; i < 4; ++i) {
    *(float4*)&qfs[t][g4 + 4 * i] = *(const float4*)&qf[rowb + 4 * i];
    *(float4*)&kfs[t][g4 + 4 * i] = *(const float4*)&kf[rowb + 4 * i];
    *(float4*)&vfs[t][g4 + 4 * i] = *(const float4*)&vf[rowb + 4 * i];
  }
  if (tid < 64) {
    int idx = bh * L_ + c * 64 + tid;
    cldS[tid] = cld[idx];
    cgS[tid] = cg[idx];
    ceS[tid] = ce[idx];
    zS[tid] = zprev[blk * 64 + tid];
  }
  __syncthreads();
  float prevEnd = (c == 0) ? 0.f : cEnd[blk - 1];
  int ts = tstar[bh];
  int i = tid >> 2, jb = (tid & 3) * 16;
  float sc[16];
#pragma unroll
  for (int jj = 0; jj < 16; ++jj) sc[jj] = 0.f;
  for (int d = 0; d < 64; d += 4) {
    float4 q4 = *(float4*)&qfs[i][d];
#pragma unroll
    for (int jj = 0; jj < 16; ++jj) {
      float4 k4 = *(float4*)&kfs[jb + jj][d];
      sc[jj] += q4.x * k4.x + q4.y * k4.y + q4.z * k4.z + q4.w * k4.w;
    }
  }
  float cldi = cldS[i];
  float den = 0.f;
  float mvals[16];
#pragma unroll
  for (int jj = 0; jj < 16; ++jj) {
    int j = jb + jj;
    float w = (j <= i) ? expf(cldi - cldS[j]) : 0.f;
    float sw = sc[jj] * w;
    den += sw * ceS[j];
    mvals[jj] = sw * cgS[j];
  }
  float dz = 0.f;
#pragma unroll
  for (int dd = 0; dd < 16; ++dd) dz += qfs[i][jb + dd] * zS[jb + dd];
  den += __shfl_xor(den, 1); den += __shfl_xor(den, 2);
  dz += __shfl_xor(dz, 1);  dz += __shfl_xor(dz, 2);
  float wi = expf(cldi - prevEnd);
  den += wi * dz + 1e-6f;
  __syncthreads();
#pragma unroll
  for (int jj = 0; jj < 16; ++jj) kfs[i][jb + jj] = mvals[jj];
  __syncthreads();
  float4 o0 = {}, o1 = {}, o2 = {}, o3 = {};
  for (int j = 0; j < 64; ++j) {
    float m = kfs[i][j];
    float4 x0 = *(float4*)&vfs[j][jb + 0];
    float4 x1 = *(float4*)&vfs[j][jb + 4];
    float4 x2 = *(float4*)&vfs[j][jb + 8];
    float4 x3 = *(float4*)&vfs[j][jb + 12];
    o0.x += m * x0.x; o0.y += m * x0.y; o0.z += m * x0.z; o0.w += m * x0.w;
    o1.x += m * x1.x; o1.y += m * x1.y; o1.z += m * x1.z; o1.w += m * x1.w;
    o2.x += m * x2.x; o2.y += m * x2.y; o2.z += m * x2.z; o2.w += m * x2.w;
    o3.x += m * x3.x; o3.y += m * x3.y; o3.z += m * x3.z; o3.w += m * x3.w;
  }
  float4 p0 = {}, p1 = {}, p2 = {}, p3 = {};
  size_t sb = (size_t)blk * 4096;
  for (int d = 0; d < 64; ++d) {
    float qd = qfs[i][d];
    float4 x0 = *(const float4*)&Sprev[sb + d * 64 + jb + 0];
    float4 x1 = *(const float4*)&Sprev[sb + d * 64 + jb + 4];
    float4 x2 = *(const float4*)&Sprev[sb + d * 64 + jb + 8];
    float4 x3 = *(const float4*)&Sprev[sb + d * 64 + jb + 12];
    p0.x += qd * x0.x; p0.y += qd * x0.y; p0.z += qd * x0.z; p0.w += qd * x0.w;
    p1.x += qd * x1.x; p1.y += qd * x1.y; p1.z += qd * x1.z; p1.w += qd * x1.w;
    p2.x += qd * x2.x; p2.y += qd * x2.y; p2.z += qd * x2.z; p2.w += qd * x2.w;
    p3.x += qd * x3.x; p3.y += qd * x3.y; p3.z += qd * x3.z; p3.w += qd * x3.w;
  }
  size_t ob = (size_t)(b * L_ + c * 64 + i) * D_ + h * 64 + jb;
  if (c * 64 + i >= ts) {
#pragma unroll
    for (int q4i = 0; q4i < 4; ++q4i) {
      float4 w4;
      w4.x = mb[jb + q4i * 4 + 0]; w4.y = mb[jb + q4i * 4 + 1];
      w4.z = mb[jb + q4i * 4 + 2]; w4.w = mb[jb + q4i * 4 + 3];
      *(float4*)&attn[ob + q4i * 4] = w4;
    }
    return;
  }
  float inv = 1.0f / den;
  float o[16];
  o[0] = (o0.x + wi * p0.x) * inv;  o[1] = (o0.y + wi * p0.y) * inv;
  o[2] = (o0.z + wi * p0.z) * inv;  o[3] = (o0.w + wi * p0.w) * inv;
  o[4] = (o1.x + wi * p1.x) * inv;  o[5] = (o1.y + wi * p1.y) * inv;
  o[6] = (o1.z + wi * p1.z) * inv;  o[7] = (o1.w + wi * p1.w) * inv;
  o[8] = (o2.x + wi * p2.x) * inv;  o[9] = (o2.y + wi * p2.y) * inv;
  o[10] = (o2.z + wi * p2.z) * inv; o[11] = (o2.w + wi * p2.w) * inv;
  o[12] = (o3.x + wi * p3.x) * inv; o[13] = (o3.y + wi * p3.y) * inv;
  o[14] = (o3.z + wi * p3.z) * inv; o[15] = (o3.w + wi * p3.w) * inv;
  float s = 0.f, s2 = 0.f;
#pragma unroll
  for (int e2 = 0; e2 < 16; ++e2) { s += o[e2]; s2 += o[e2] * o[e2]; }
  s += __shfl_xor(s, 1);  s += __shfl_xor(s, 2);
  s2 += __shfl_xor(s2, 1); s2 += __shfl_xor(s2, 2);
  float mu = s * (1.f / 64.f);
  float var = s2 * (1.f / 64.f) - mu * mu;
  float rs = rsqrtf(var + 1e-5f);
#pragma unroll
  for (int q4i = 0; q4i < 4; ++q4i) {
    float4 w4;
    w4.x = (o[q4i * 4 + 0] - mu) * rs * mg[jb + q4i * 4 + 0] + mb[jb + q4i * 4 + 0];
    w4.y = (o[q4i * 4 + 1] - mu) * rs * mg[jb + q4i * 4 + 1] + mb[jb + q4i * 4 + 1];
    w4.z = (o[q4i * 4 + 2] - mu) * rs * mg[jb + q4i * 4 + 2] + mb[jb + q4i * 4 + 2];
    w4.w = (o[q4i * 4 + 3] - mu) * rs * mg[jb + q4i * 4 + 3] + mb[jb + q4i * 4 + 3];
    *(float4*)&attn[ob + q4i * 4] = w4;
  }
}

extern "C" void kernel_launch(void* const* d_in, const int* in_sizes, int n_in,
                              void* d_out, int out_size, void* d_ws, size_t ws_size,
                              hipStream_t stream) {
  const float* x     = (const float*)d_in[0];
  const float* Wqkv  = (const float*)d_in[1];
  const float* bqkv  = (const float*)d_in[2];
  const float* Wb1   = (const float*)d_in[3];
  const float* Wb2   = (const float*)d_in[4];
  const float* temp  = (const float*)d_in[5];
  const float* Wproj = (const float*)d_in[6];
  const float* bproj = (const float*)d_in[7];
  const float* lng   = (const float*)d_in[8];
  const float* lnb   = (const float*)d_in[9];
  const float* memg  = (const float*)d_in[10];
  const float* memb  = (const float*)d_in[11];
  float* out0 = (float*)d_out;
  float* gate = out0 + BLD_;

  static const int expect[12] = {1572864, 1769472, 2304, 98304, 7680, 1,
                                 589824, 768, 768, 768, 64, 64};
  int bad = (n_in == 12) ? -1 : 99;
  if (bad < 0) for (int i = 0; i < 12; ++i) if (in_sizes[i] != expect[i]) { bad = i; break; }
  size_t need = (size_t)(4 * BLD_ + 262144 + 4 * 24576) * sizeof(float);  // 26.61 MB (proven)
  if (bad >= 0) { sentinel_kernel<<<1, 1, 0, stream>>>(out0, 3.0e6f, (float)bad); return; }
  if (ws_size < need) { sentinel_kernel<<<1, 1, 0, stream>>>(out0, 1.0e6f, (float)(ws_size >> 20)); return; }

  float* ws   = (float*)d_ws;
  float* xn   = ws;                  // BLD_; holds murs (4096) until QKV, then T/Sprev
  float* qfb  = xn + BLD_;           // BLD_; reused as attn by chunk_out (same rows)
  float* kfb  = qfb + BLD_;
  float* vfb  = kfb + BLD_;
  float* h1   = vfb + BLD_;          // 262144 scratch region -> zc/zprev/cEnd/tstar
  float* cgb  = h1 + 262144;
  float* ceb  = cgb + 24576;
  float* ldb  = ceb + 24576;
  float* cldb = ldb + 24576;
  float* murs = xn;                  // 4096 floats; dead after QKV (T written later)
  float* Tb   = xn;                  // alias: T and (after in-place scan) Sprev
  float* zcb  = h1;
  float* zpv  = h1 + 24576;
  float* cEnd = h1 + 49152;          // 384
  int*   tstar = (int*)(h1 + 49536); // 48
  float* attn = qfb;                 // alias: chunk_out writes exactly the rows it read

  bottleneck_kernel<<<BL_, 256, 0, stream>>>(x, Wb1, Wb2, temp, murs, gate, cgb, ceb, ldb);
  gemm_qkv<<<dim3(36, 32), 256, 0, stream>>>(x, murs, lng, lnb, Wqkv, bqkv, qfb, kfb, vfb);
  cldinf_kernel<<<BH_, 64, 0, stream>>>(ldb, ceb, kfb, cldb, cEnd, tstar);
  chunk_sum_kernel<<<BH_ * NC_, 256, 0, stream>>>(kfb, vfb, cgb, ceb, cldb, cEnd, Tb, zcb);
  scan_kernel<<<BH_, 256, 0, stream>>>(Tb, zcb, cEnd, zpv);
  chunk_out_kernel<<<BH_ * NC_, 256, 0, stream>>>(qfb, kfb, vfb, cgb, ceb, cldb, cEnd,
                                                  Tb, zpv, tstar, memg, memb, attn);
  gemm_proj<<<dim3(12, 32), 256, 0, stream>>>(attn, Wproj, bproj, out0, 768, 768);
}